// Round 1
// 4582.455 us; speedup vs baseline: 1.0542x; 1.0542x over previous
//
#include <hip/hip_runtime.h>
#include <hip/hip_bf16.h>
#include <math.h>

#define B_   8
#define S_   512
#define H_   768
#define L_   12
#define NHD_ 12
#define DH_  64
#define DFF_ 3072
#define NL_  19

#define NCH_ 32   // CRF chunks per batch
#define CHL_ 16   // timesteps per chunk (last chunk has 15)

typedef __bf16 bf16x8 __attribute__((ext_vector_type(8)));
typedef float  f32x4  __attribute__((ext_vector_type(4)));

__device__ __forceinline__ unsigned short f2bf(float f) {
    unsigned int u = __float_as_uint(f);
    u = (u + 0x7fffu + ((u >> 16) & 1u)) >> 16;
    return (unsigned short)u;
}

__device__ __forceinline__ float gelu_f(float x) {
    const float c = 0.7978845608028654f; // sqrt(2/pi)
    float x3 = x * x * x;
    return 0.5f * x * (1.0f + tanhf(c * (x + 0.044715f * x3)));
}

// async global->LDS, 16B per lane; lds dest must be wave-uniform base + lane*16
__device__ __forceinline__ void load_lds16(const unsigned short* g, unsigned short* l) {
    __builtin_amdgcn_global_load_lds(
        (const __attribute__((address_space(1))) unsigned int*)g,
        (__attribute__((address_space(3))) unsigned int*)l,
        16, 0, 0);
}

// ---------------------------------------------------------------------------
// Per-layer weight prep: 6 transposes (fp32 [K][N] -> bf16 [N][K]) + qkv bias
// concat, one launch. Tile map: [0,576) four HxH weights (144 tiles each),
// [576,1152) W1 (48x12), [1152,1728) W2 (12x48), [1728,1737) bias concat.
// ---------------------------------------------------------------------------
__global__ __launch_bounds__(256) void prep_layer(
    const float* __restrict__ Wq, const float* __restrict__ Wk,
    const float* __restrict__ Wv, const float* __restrict__ Wo,
    const float* __restrict__ W1, const float* __restrict__ W2,
    const float* __restrict__ bq, const float* __restrict__ bk,
    const float* __restrict__ bv,
    unsigned short* __restrict__ WqkvT, unsigned short* __restrict__ WoT,
    unsigned short* __restrict__ W1T, unsigned short* __restrict__ W2T,
    float* __restrict__ biasc)
{
    __shared__ float t[64][65];
    const int tid = threadIdx.x;
    const int id = blockIdx.x;

    if (id >= 1728) {
        int i = (id - 1728) * 256 + tid;
        if (i < 3 * H_) biasc[i] = (i < H_) ? bq[i] : (i < 2 * H_ ? bk[i - H_] : bv[i - 2 * H_]);
        return;
    }

    const float* src; unsigned short* dst; int K, N, bx, by;
    if (id < 576) {
        int wsel = id / 144, tt = id % 144;
        bx = tt % 12; by = tt / 12; K = H_; N = H_;
        src = (wsel == 0) ? Wq : (wsel == 1) ? Wk : (wsel == 2) ? Wv : Wo;
        dst = (wsel < 3) ? (WqkvT + (size_t)wsel * H_ * H_) : WoT;
    } else if (id < 1152) {
        int tt = id - 576; bx = tt % 48; by = tt / 48; K = H_; N = DFF_; src = W1; dst = W1T;
    } else {
        int tt = id - 1152; bx = tt % 12; by = tt / 12; K = DFF_; N = H_; src = W2; dst = W2T;
    }

    const int n0 = bx * 64, k0 = by * 64;
    #pragma unroll
    for (int p = 0; p < 16; ++p) {
        int idx = p * 256 + tid;
        int i = idx >> 6, j = idx & 63;
        t[i][j] = src[(size_t)(k0 + i) * N + n0 + j];
    }
    __syncthreads();
    #pragma unroll
    for (int p = 0; p < 4; ++p) {
        int q = p * 256 + tid;
        int n = q >> 4, kq = q & 15;
        unsigned int w0 = (unsigned int)f2bf(t[kq * 4 + 0][n]) | ((unsigned int)f2bf(t[kq * 4 + 1][n]) << 16);
        unsigned int w1 = (unsigned int)f2bf(t[kq * 4 + 2][n]) | ((unsigned int)f2bf(t[kq * 4 + 3][n]) << 16);
        uint2 w; w.x = w0; w.y = w1;
        *(uint2*)(dst + (size_t)(n0 + n) * K + k0 + kq * 4) = w;
    }
}

// ---------------------------------------------------------------------------
// bf16 MFMA GEMM with async global->LDS staging (m97 structure).
// C[M,N] = epi(A[M,K] @ Bt[N,K]^T + bias); EPI: 0 fp32, 1 gelu->bf16, 2 +res fp32
// 128x128 tile, 256 thr (4 waves 2x2). LDS unpadded: chunk i (16B) at i*16,
// i = row*4 + kchunk — exactly the lane-contiguous order global_load_lds needs.
// ---------------------------------------------------------------------------
template <int EPI>
__global__ __launch_bounds__(256) void gemm_bf16(
    const unsigned short* __restrict__ A,   // [M][K] bf16
    const unsigned short* __restrict__ Bt,  // [N][K] bf16
    const float* __restrict__ bias,         // [N]
    const float* __restrict__ R,            // [M][N] residual (EPI==2)
    float* __restrict__ Cf,                 // fp32 out (EPI 0,2)
    unsigned short* __restrict__ Cb,        // bf16 out (EPI 1)
    int M, int N, int K)
{
    __shared__ __align__(16) unsigned short As[128 * 32];
    __shared__ __align__(16) unsigned short Bs[128 * 32];
    const int tid  = threadIdx.x;
    const int lane = tid & 63;
    const int wave = tid >> 6;
    const int wm = wave >> 1, wn = wave & 1;
    const int mbase = blockIdx.y * 128;
    const int nbase = blockIdx.x * 128;

    f32x4 acc[4][4];
    #pragma unroll
    for (int mi = 0; mi < 4; ++mi)
        #pragma unroll
        for (int ni = 0; ni < 4; ++ni) acc[mi][ni] = (f32x4){0.f, 0.f, 0.f, 0.f};

    const int crow = tid >> 2;           // 0..63
    const int kc   = tid & 3;            // 16B chunk within 32-elem k-slab
    const unsigned short* ag0 = A  + (size_t)(mbase + crow) * K + kc * 8;
    const unsigned short* ag1 = A  + (size_t)(mbase + 64 + crow) * K + kc * 8;
    const unsigned short* bg0 = Bt + (size_t)(nbase + crow) * K + kc * 8;
    const unsigned short* bg1 = Bt + (size_t)(nbase + 64 + crow) * K + kc * 8;
    unsigned short* la0 = As + (size_t)tid * 8;
    unsigned short* la1 = As + (size_t)(256 + tid) * 8;
    unsigned short* lb0 = Bs + (size_t)tid * 8;
    unsigned short* lb1 = Bs + (size_t)(256 + tid) * 8;

    const int fr = lane & 15;
    const int fc = lane >> 4;

    for (int kk = 0; kk < K; kk += 32) {
        load_lds16(ag0 + kk, la0);
        load_lds16(ag1 + kk, la1);
        load_lds16(bg0 + kk, lb0);
        load_lds16(bg1 + kk, lb1);
        __syncthreads();

        bf16x8 af[4], bf[4];
        #pragma unroll
        for (int mi = 0; mi < 4; ++mi)
            af[mi] = *(const bf16x8*)&As[(size_t)(wm * 64 + mi * 16 + fr) * 32 + fc * 8];
        #pragma unroll
        for (int ni = 0; ni < 4; ++ni)
            bf[ni] = *(const bf16x8*)&Bs[(size_t)(wn * 64 + ni * 16 + fr) * 32 + fc * 8];

        #pragma unroll
        for (int mi = 0; mi < 4; ++mi)
            #pragma unroll
            for (int ni = 0; ni < 4; ++ni)
                acc[mi][ni] = __builtin_amdgcn_mfma_f32_16x16x32_bf16(
                    af[mi], bf[ni], acc[mi][ni], 0, 0, 0);
        __syncthreads();
    }

    const int r0 = (lane >> 4) * 4;
    const int c0 = lane & 15;
    #pragma unroll
    for (int mi = 0; mi < 4; ++mi) {
        const int gm = mbase + wm * 64 + mi * 16 + r0;
        #pragma unroll
        for (int ni = 0; ni < 4; ++ni) {
            const int gn = nbase + wn * 64 + ni * 16 + c0;
            const float bv = bias[gn];
            #pragma unroll
            for (int r = 0; r < 4; ++r) {
                float vv = acc[mi][ni][r] + bv;
                const size_t off = (size_t)(gm + r) * N + gn;
                if (EPI == 0)      Cf[off] = vv;
                else if (EPI == 1) Cb[off] = f2bf(gelu_f(vv));
                else               Cf[off] = vv + R[off];
            }
        }
    }
}

// ---------------------------------------------------------------------------
// Flash-style attention, fp32 VALU (unchanged).
// ---------------------------------------------------------------------------
__global__ __launch_bounds__(256) void attn2(
    const float* __restrict__ qkv, const int* __restrict__ mask,
    unsigned short* __restrict__ ctxb)
{
    const int qt = blockIdx.x, h = blockIdx.y, b = blockIdx.z;
    const int tid = threadIdx.x;
    const int qr = tid >> 2;
    const int kg = tid & 3;

    __shared__ __align__(16) float Ks[64 * 64];
    __shared__ __align__(16) float Vs[64 * 64];
    __shared__ float Ps[64 * 65];
    __shared__ float Ms[64];

    const size_t base = (size_t)b * S_ * 2304 + h * 64;
    const float* qp = qkv + base + (size_t)(qt * 64 + qr) * 2304;
    f32x4 q4[16];
    #pragma unroll
    for (int c = 0; c < 16; ++c) q4[c] = *(const f32x4*)(qp + c * 4);

    float m = -1e30f, l = 0.f;
    float acc[16];
    #pragma unroll
    for (int i = 0; i < 16; ++i) acc[i] = 0.f;

    for (int kt = 0; kt < 8; ++kt) {
        __syncthreads();
        #pragma unroll
        for (int p = 0; p < 4; ++p) {
            int f = p * 256 + tid;
            int row = f >> 4, c = f & 15;
            int scc = c ^ (row >> 4);
            const float* kp = qkv + base + 768 + (size_t)(kt * 64 + row) * 2304 + c * 4;
            *(f32x4*)&Ks[row * 64 + scc * 4] = *(const f32x4*)kp;
            *(f32x4*)&Vs[row * 64 + scc * 4] = *(const f32x4*)(kp + 768);
        }
        if (tid < 64)
            Ms[tid] = (1.0f - (float)mask[b * S_ + kt * 64 + tid]) * -1e9f;
        __syncthreads();

        float s[16];
        #pragma unroll
        for (int j = 0; j < 16; ++j) s[j] = 0.f;
        #pragma unroll
        for (int c = 0; c < 16; ++c) {
            f32x4 qv = q4[c];
            #pragma unroll
            for (int j = 0; j < 16; ++j) {
                f32x4 kv = *(const f32x4*)&Ks[(kg * 16 + j) * 64 + ((c ^ kg) << 2)];
                s[j] = fmaf(qv[0], kv[0], fmaf(qv[1], kv[1],
                       fmaf(qv[2], kv[2], fmaf(qv[3], kv[3], s[j]))));
            }
        }

        float tm = -1e30f;
        #pragma unroll
        for (int j = 0; j < 16; ++j) {
            s[j] = s[j] * 0.125f + Ms[kg * 16 + j];
            tm = fmaxf(tm, s[j]);
        }
        tm = fmaxf(tm, __shfl_xor(tm, 1));
        tm = fmaxf(tm, __shfl_xor(tm, 2));
        float mnew = fmaxf(m, tm);
        float alpha = __expf(m - mnew);
        float ps = 0.f;
        #pragma unroll
        for (int j = 0; j < 16; ++j) {
            float e = __expf(s[j] - mnew);
            Ps[qr * 65 + kg * 16 + j] = e;
            ps += e;
        }
        ps += __shfl_xor(ps, 1);
        ps += __shfl_xor(ps, 2);
        l = l * alpha + ps;
        m = mnew;
        #pragma unroll
        for (int i = 0; i < 16; ++i) acc[i] *= alpha;
        __syncthreads();

        for (int kk = 0; kk < 64; ++kk) {
            float p = Ps[qr * 65 + kk];
            int swz = kk >> 4;
            #pragma unroll
            for (int i4 = 0; i4 < 4; ++i4) {
                f32x4 vv = *(const f32x4*)&Vs[kk * 64 + (((kg * 4 + i4) ^ swz) << 2)];
                acc[i4 * 4 + 0] = fmaf(p, vv[0], acc[i4 * 4 + 0]);
                acc[i4 * 4 + 1] = fmaf(p, vv[1], acc[i4 * 4 + 1]);
                acc[i4 * 4 + 2] = fmaf(p, vv[2], acc[i4 * 4 + 2]);
                acc[i4 * 4 + 3] = fmaf(p, vv[3], acc[i4 * 4 + 3]);
            }
        }
    }

    float invl = 1.0f / l;
    unsigned short* op = ctxb + (size_t)(b * S_ + qt * 64 + qr) * H_ + h * 64 + kg * 16;
    #pragma unroll
    for (int i = 0; i < 16; ++i) op[i] = f2bf(acc[i] * invl);
}

// ---------------------------------------------------------------------------
// Row LayerNorm; writes fp32 + bf16 copies.
// ---------------------------------------------------------------------------
__global__ __launch_bounds__(256) void ln_kernel(
    const float* __restrict__ in, const float* __restrict__ sc,
    const float* __restrict__ bi, float* __restrict__ out,
    unsigned short* __restrict__ outb)
{
    const int row = blockIdx.x;
    const int tid = threadIdx.x;
    const float* x = in + (size_t)row * H_;
    float v[3], s0 = 0.f, s1 = 0.f;
    #pragma unroll
    for (int r = 0; r < 3; ++r) {
        v[r] = x[tid + r * 256];
        s0 += v[r]; s1 += v[r] * v[r];
    }
    __shared__ float red[8];
    __shared__ float stat[2];
    #pragma unroll
    for (int o = 32; o > 0; o >>= 1) { s0 += __shfl_down(s0, o); s1 += __shfl_down(s1, o); }
    if ((tid & 63) == 0) { red[tid >> 6] = s0; red[4 + (tid >> 6)] = s1; }
    __syncthreads();
    if (tid == 0) {
        float t0 = red[0] + red[1] + red[2] + red[3];
        float t1 = red[4] + red[5] + red[6] + red[7];
        float mean = t0 / H_;
        float var  = t1 / H_ - mean * mean;
        stat[0] = mean;
        stat[1] = rsqrtf(var + 1e-12f);
    }
    __syncthreads();
    float mean = stat[0], rstd = stat[1];
    float* o = out + (size_t)row * H_;
    unsigned short* ob = outb + (size_t)row * H_;
    #pragma unroll
    for (int r = 0; r < 3; ++r) {
        int i = tid + r * 256;
        float rr = (v[r] - mean) * rstd * sc[i] + bi[i];
        o[i] = rr;
        ob[i] = f2bf(rr);
    }
}

__global__ __launch_bounds__(256) void embed_ln_kernel(
    const int* __restrict__ ids, const float* __restrict__ tok,
    const float* __restrict__ pos, const float* __restrict__ sc,
    const float* __restrict__ bi, float* __restrict__ out,
    unsigned short* __restrict__ outb)
{
    const int row = blockIdx.x;
    const int spos = row & (S_ - 1);
    const int tid = threadIdx.x;
    const int id = ids[row];
    const float* t = tok + (size_t)id * H_;
    const float* p = pos + (size_t)spos * H_;
    float v[3], s0 = 0.f, s1 = 0.f;
    #pragma unroll
    for (int r = 0; r < 3; ++r) {
        int i = tid + r * 256;
        v[r] = t[i] + p[i];
        s0 += v[r]; s1 += v[r] * v[r];
    }
    __shared__ float red[8];
    __shared__ float stat[2];
    #pragma unroll
    for (int o = 32; o > 0; o >>= 1) { s0 += __shfl_down(s0, o); s1 += __shfl_down(s1, o); }
    if ((tid & 63) == 0) { red[tid >> 6] = s0; red[4 + (tid >> 6)] = s1; }
    __syncthreads();
    if (tid == 0) {
        float t0 = red[0] + red[1] + red[2] + red[3];
        float t1 = red[4] + red[5] + red[6] + red[7];
        float mean = t0 / H_;
        float var  = t1 / H_ - mean * mean;
        stat[0] = mean;
        stat[1] = rsqrtf(var + 1e-12f);
    }
    __syncthreads();
    float mean = stat[0], rstd = stat[1];
    float* o = out + (size_t)row * H_;
    unsigned short* ob = outb + (size_t)row * H_;
    #pragma unroll
    for (int r = 0; r < 3; ++r) {
        int i = tid + r * 256;
        float rr = (v[r] - mean) * rstd * sc[i] + bi[i];
        o[i] = rr;
        ob[i] = f2bf(rr);
    }
}

// ---------------------------------------------------------------------------
// Classifier SIMT GEMM (N=19, tiny) — fp32.
// ---------------------------------------------------------------------------
__global__ __launch_bounds__(256) void gemm_cls(
    const float* __restrict__ A, const float* __restrict__ W,
    const float* __restrict__ bias, float* __restrict__ C, int M, int N, int K)
{
    __shared__ float As[16][65];
    __shared__ float Ws[16][64];
    const int tid = threadIdx.x;
    const int tx = tid & 15;
    const int ty = tid >> 4;
    const int mbase = blockIdx.y * 64;
    const int nbase = blockIdx.x * 64;
    float acc[4][4] = {};
    for (int kk = 0; kk < K; kk += 16) {
        #pragma unroll
        for (int r = 0; r < 4; ++r) {
            int idx = r * 256 + tid;
            int mm = idx >> 4, k4 = idx & 15;
            As[k4][mm] = A[(size_t)(mbase + mm) * K + kk + k4];
        }
        #pragma unroll
        for (int r = 0; r < 4; ++r) {
            int idx = r * 256 + tid;
            int n = idx & 63, k4 = idx >> 6;
            int gn = nbase + n;
            Ws[k4][n] = (gn < N) ? W[(size_t)(kk + k4) * N + gn] : 0.0f;
        }
        __syncthreads();
        #pragma unroll
        for (int k = 0; k < 16; ++k) {
            float a[4], w[4];
            #pragma unroll
            for (int i = 0; i < 4; ++i) a[i] = As[k][ty * 4 + i];
            #pragma unroll
            for (int j = 0; j < 4; ++j) w[j] = Ws[k][tx * 4 + j];
            #pragma unroll
            for (int i = 0; i < 4; ++i)
                #pragma unroll
                for (int j = 0; j < 4; ++j)
                    acc[i][j] = fmaf(a[i], w[j], acc[i][j]);
        }
        __syncthreads();
    }
    #pragma unroll
    for (int i = 0; i < 4; ++i) {
        int gm = mbase + ty * 4 + i;
        #pragma unroll
        for (int j = 0; j < 4; ++j) {
            int gn = nbase + tx * 4 + j;
            if (gn < N) C[(size_t)gm * N + gn] = acc[i][j] + bias[gn];
        }
    }
}

// ---------------------------------------------------------------------------
// CRF numerator per batch (unchanged)
// ---------------------------------------------------------------------------
__global__ __launch_bounds__(256) void crf_num_kernel(
    const float* __restrict__ logits, const int* __restrict__ labels,
    const int* __restrict__ mask, const float* __restrict__ start_trans,
    const float* __restrict__ end_trans, const float* __restrict__ trans,
    float* __restrict__ numb)
{
    const int b = blockIdx.x;
    const int tid = threadIdx.x;
    float lsum = 0.f, lmask = 0.f;
    for (int t = tid; t < S_; t += 256) {
        float mf = (float)mask[b * S_ + t];
        lmask += mf;
        if (t >= 1) {
            int lp = labels[b * S_ + t - 1];
            int lc = labels[b * S_ + t];
            float em = logits[((size_t)b * S_ + t) * NL_ + lc];
            lsum += (trans[lp * NL_ + lc] + em) * mf;
        }
    }
    __shared__ float red[8];
    #pragma unroll
    for (int o = 32; o > 0; o >>= 1) { lsum += __shfl_down(lsum, o); lmask += __shfl_down(lmask, o); }
    if ((tid & 63) == 0) { red[tid >> 6] = lsum; red[4 + (tid >> 6)] = lmask; }
    __syncthreads();
    if (tid == 0) {
        float ts = red[0] + red[1] + red[2] + red[3];
        float tm = red[4] + red[5] + red[6] + red[7];
        int l0 = labels[b * S_];
        float nm = start_trans[l0] + logits[(size_t)b * S_ * NL_ + l0] + ts;
        int last = (int)tm - 1;
        int lt = labels[b * S_ + last];
        nm += end_trans[lt];
        numb[b] = nm;
    }
}

// ---------------------------------------------------------------------------
// CRF forward, parallel-scan rewrite (log-semiring associative scan).
//
// The recursion alpha_t = alpha_{t-1} (x) M_t, with
//   M_t[i][j] = trans[i][j] + em_t[j]  (mask_t=1)  |  I (mask_t=0),
// is a chain of semiring matrix products -> associative.
//
// Phase 1 (crf_chunk_kernel): 32 chunks x 8 batches = 256 blocks; each folds
// its 16 timesteps into a 19x19 chunk transfer matrix P_c held in LDS.
// Uses P (x) M_t = [lse_k(P[i][k] + trans[k][j])] + em_t[j] so the emission
// add is hoisted out of the lse.
//
// Phase 2 (crf_combine_kernel): per batch, load all 32 chunk matrices into
// LDS (46 KB) and tree-reduce in 5 levels of in-place 19x19x19 log-matmuls
// (register-buffered between read/write with static indexing), then apply
// alpha0 and end_trans for the denominator.
// ---------------------------------------------------------------------------
__global__ __launch_bounds__(384) void crf_chunk_kernel(
    const float* __restrict__ logits, const int* __restrict__ mask,
    const float* __restrict__ trans, float* __restrict__ Pg)
{
    const int c = blockIdx.x, b = blockIdx.y;
    const int tid = threadIdx.x;
    const bool act = tid < NL_ * NL_;
    const int i = tid / NL_;
    const int j = tid - i * NL_;

    const int t0 = 1 + c * CHL_;
    const int nt = min(CHL_, S_ - t0);       // 16, except last chunk = 15

    __shared__ float P[NL_][20];
    __shared__ float tr_s[NL_ * NL_];
    __shared__ float em_s[CHL_ * NL_];
    __shared__ int mk[CHL_];

    for (int f = tid; f < NL_ * NL_; f += 384) tr_s[f] = trans[f];
    for (int f = tid; f < nt * NL_; f += 384)
        em_s[f] = logits[((size_t)b * S_ + t0) * NL_ + f];
    if (tid < nt) mk[tid] = mask[b * S_ + t0 + tid];
    __syncthreads();

    float trcol[NL_];                          // trans[:, j], static-indexed only
    if (act) {
        #pragma unroll
        for (int k = 0; k < NL_; ++k) trcol[k] = tr_s[k * NL_ + j];
        // absorb first step of the chunk into the init
        float p0;
        if (mk[0] > 0) p0 = tr_s[i * NL_ + j] + em_s[j];
        else           p0 = (i == j) ? 0.f : -1e30f;
        P[i][j] = p0;
    }
    __syncthreads();

    for (int tt = 1; tt < nt; ++tt) {
        float nv = 0.f;
        if (act) {
            float v[NL_];
            float vmax = -3e38f;
            #pragma unroll
            for (int k = 0; k < NL_; ++k) {
                v[k] = P[i][k] + trcol[k];     // row read = LDS broadcast
                vmax = fmaxf(vmax, v[k]);
            }
            float s = 0.f;
            #pragma unroll
            for (int k = 0; k < NL_; ++k) s += __expf(v[k] - vmax);
            nv = vmax + __logf(s) + em_s[tt * NL_ + j];
        }
        __syncthreads();
        if (act && mk[tt] > 0) P[i][j] = nv;   // mask=0 -> P unchanged (== P (x) I)
        __syncthreads();
    }

    if (act) Pg[((size_t)b * NCH_ + c) * (NL_ * NL_) + tid] = P[i][j];
}

__global__ __launch_bounds__(384) void crf_combine_kernel(
    const float* __restrict__ Pg, const float* __restrict__ logits,
    const float* __restrict__ start_trans, const float* __restrict__ end_trans,
    float* __restrict__ denb)
{
    const int b = blockIdx.x;
    const int tid = threadIdx.x;
    __shared__ float Q[NCH_ * NL_ * NL_];      // 32 * 361 * 4B = 46.2 KB
    __shared__ float fin[NL_];

    for (int w = tid; w < NCH_ * NL_ * NL_; w += 384)
        Q[w] = Pg[(size_t)b * NCH_ * NL_ * NL_ + w];
    __syncthreads();

    // in-place tree reduction: pairs (2p, 2p+1) -> slot p; order preserved
    for (int m = NCH_ / 2; m >= 1; m >>= 1) {
        const int items = m * NL_ * NL_;
        float res[16];                          // static-indexed (rule #20)
        #pragma unroll
        for (int r = 0; r < 16; ++r) {
            const int w = tid + r * 384;
            if (w < items) {
                const int p = w / (NL_ * NL_);
                const int e = w - p * (NL_ * NL_);
                const int ii = e / NL_;
                const int jj = e - ii * NL_;
                const float* Lm = &Q[(2 * p) * NL_ * NL_ + ii * NL_];
                const float* Rm = &Q[(2 * p + 1) * NL_ * NL_ + jj];
                float v[NL_];
                float vmax = -3e38f;
                #pragma unroll
                for (int k = 0; k < NL_; ++k) {
                    v[k] = Lm[k] + Rm[k * NL_];
                    vmax = fmaxf(vmax, v[k]);
                }
                float s = 0.f;
                #pragma unroll
                for (int k = 0; k < NL_; ++k) s += __expf(v[k] - vmax);
                res[r] = vmax + __logf(s);
            }
        }
        __syncthreads();
        #pragma unroll
        for (int r = 0; r < 16; ++r) {
            const int w = tid + r * 384;
            if (w < items) Q[w] = res[r];      // out idx = p*361 + e = w
        }
        __syncthreads();
    }

    // den_b = lse_j( lse_i(alpha0[i] + Ptot[i][j]) + end_trans[j] )
    if (tid < NL_) {
        float v[NL_];
        float vmax = -3e38f;
        #pragma unroll
        for (int k = 0; k < NL_; ++k) {
            v[k] = start_trans[k] + logits[(size_t)b * S_ * NL_ + k] + Q[k * NL_ + tid];
            vmax = fmaxf(vmax, v[k]);
        }
        float s = 0.f;
        #pragma unroll
        for (int k = 0; k < NL_; ++k) s += __expf(v[k] - vmax);
        fin[tid] = vmax + __logf(s) + end_trans[tid];
    }
    __syncthreads();
    if (tid == 0) {
        float vmax = -3e38f;
        #pragma unroll
        for (int k = 0; k < NL_; ++k) vmax = fmaxf(vmax, fin[k]);
        float s = 0.f;
        #pragma unroll
        for (int k = 0; k < NL_; ++k) s += __expf(fin[k] - vmax);
        denb[b] = vmax + __logf(s);
    }
}

__global__ void finalize_kernel(const float* __restrict__ numb,
                                const float* __restrict__ denb,
                                float* __restrict__ out)
{
    if (threadIdx.x == 0 && blockIdx.x == 0) {
        float s = 0.f;
        for (int b = 0; b < B_; ++b) s += denb[b] - numb[b];
        out[0] = s;
    }
}

// ---------------------------------------------------------------------------
extern "C" void kernel_launch(void* const* d_in, const int* in_sizes, int n_in,
                              void* d_out, int out_size, void* d_ws, size_t ws_size,
                              hipStream_t stream)
{
    const int*   input_ids = (const int*)d_in[0];
    const int*   attn_mask = (const int*)d_in[1];
    const int*   labels    = (const int*)d_in[2];
    const float* token_emb = (const float*)d_in[3];
    const float* pos_emb   = (const float*)d_in[4];
    const float* ln_emb_s  = (const float*)d_in[5];
    const float* ln_emb_b  = (const float*)d_in[6];
    const float* Wq  = (const float*)d_in[7];
    const float* bq  = (const float*)d_in[8];
    const float* Wk  = (const float*)d_in[9];
    const float* bk  = (const float*)d_in[10];
    const float* Wv  = (const float*)d_in[11];
    const float* bv  = (const float*)d_in[12];
    const float* Wo  = (const float*)d_in[13];
    const float* bo  = (const float*)d_in[14];
    const float* ln1s = (const float*)d_in[15];
    const float* ln1b = (const float*)d_in[16];
    const float* W1  = (const float*)d_in[17];
    const float* b1  = (const float*)d_in[18];
    const float* W2  = (const float*)d_in[19];
    const float* b2  = (const float*)d_in[20];
    const float* ln2s = (const float*)d_in[21];
    const float* ln2b = (const float*)d_in[22];
    const float* cls_W = (const float*)d_in[23];
    const float* cls_b = (const float*)d_in[24];
    const float* start_trans = (const float*)d_in[25];
    const float* end_trans   = (const float*)d_in[26];
    const float* trans       = (const float*)d_in[27];

    char* base = (char*)d_ws;
    const int M = B_ * S_;                                  // 4096
    float*          qkv   = (float*)base;                    // [M][2304] fp32
    unsigned short* hbb   = (unsigned short*)base;           // [M][3072] bf16 (aliases qkv)
    size_t off = (size_t)M * 2304 * 4;
    float*          x     = (float*)(base + off); off += (size_t)M * H_ * 4;
    float*          y     = (float*)(base + off); off += (size_t)M * H_ * 4;
    unsigned short* xb    = (unsigned short*)(base + off); off += (size_t)M * H_ * 2;
    unsigned short* ctxb  = (unsigned short*)(base + off); off += (size_t)M * H_ * 2;
    unsigned short* WqkvT = (unsigned short*)(base + off); off += (size_t)3 * H_ * H_ * 2;
    unsigned short* WoT   = (unsigned short*)(base + off); off += (size_t)H_ * H_ * 2;
    unsigned short* W1T   = (unsigned short*)(base + off); off += (size_t)DFF_ * H_ * 2;
    unsigned short* W2T   = (unsigned short*)(base + off); off += (size_t)H_ * DFF_ * 2;
    float*          biasc = (float*)(base + off); off += 3 * H_ * 4 + 256;
    float*          logits= (float*)(base + off); off += (size_t)M * NL_ * 4;
    float*          numb  = (float*)(base + off); off += 32;
    float*          denb  = (float*)(base + off); off += 32;
    float*          Pg    = (float*)(base + off); off += (size_t)B_ * NCH_ * NL_ * NL_ * 4;

    dim3 blk(256);
    embed_ln_kernel<<<M, blk, 0, stream>>>(input_ids, token_emb, pos_emb, ln_emb_s, ln_emb_b, x, xb);

    for (int l = 0; l < L_; ++l) {
        const size_t oHH = (size_t)l * H_ * H_;
        const size_t oHF = (size_t)l * H_ * DFF_;
        prep_layer<<<1737, blk, 0, stream>>>(
            Wq + oHH, Wk + oHH, Wv + oHH, Wo + oHH, W1 + oHF, W2 + oHF,
            bq + l * H_, bk + l * H_, bv + l * H_,
            WqkvT, WoT, W1T, W2T, biasc);

        gemm_bf16<0><<<dim3(18, 32), blk, 0, stream>>>(xb, WqkvT, biasc, nullptr, qkv, nullptr, M, 3 * H_, H_);
        attn2<<<dim3(8, NHD_, B_), blk, 0, stream>>>(qkv, attn_mask, ctxb);
        gemm_bf16<2><<<dim3(6, 32), blk, 0, stream>>>(ctxb, WoT, bo + l * H_, x, y, nullptr, M, H_, H_);
        ln_kernel<<<M, blk, 0, stream>>>(y, ln1s + l * H_, ln1b + l * H_, x, xb);
        gemm_bf16<1><<<dim3(24, 32), blk, 0, stream>>>(xb, W1T, b1 + l * DFF_, nullptr, nullptr, hbb, M, DFF_, H_);
        gemm_bf16<2><<<dim3(6, 32), blk, 0, stream>>>(hbb, W2T, b2 + l * H_, x, y, nullptr, M, H_, DFF_);
        ln_kernel<<<M, blk, 0, stream>>>(y, ln2s + l * H_, ln2b + l * H_, x, xb);
    }

    gemm_cls<<<dim3(1, M / 64), blk, 0, stream>>>(x, cls_W, cls_b, logits, M, NL_, H_);
    crf_num_kernel<<<B_, blk, 0, stream>>>(logits, labels, attn_mask, start_trans, end_trans, trans, numb);
    crf_chunk_kernel<<<dim3(NCH_, B_), dim3(384), 0, stream>>>(logits, attn_mask, trans, Pg);
    crf_combine_kernel<<<B_, dim3(384), 0, stream>>>(Pg, logits, start_trans, end_trans, denb);
    finalize_kernel<<<1, 64, 0, stream>>>(numb, denb, (float*)d_out);
}

// Round 2
// 3160.967 us; speedup vs baseline: 1.5283x; 1.4497x over previous
//
#include <hip/hip_runtime.h>
#include <hip/hip_bf16.h>
#include <math.h>

#define B_   8
#define S_   512
#define H_   768
#define L_   12
#define NHD_ 12
#define DH_  64
#define DFF_ 3072
#define NL_  19

#define NCH_ 32   // CRF chunks per batch
#define CHL_ 16   // timesteps per chunk (last chunk has 15)

typedef __bf16 bf16x8 __attribute__((ext_vector_type(8)));
typedef float  f32x4  __attribute__((ext_vector_type(4)));

__device__ __forceinline__ unsigned short f2bf(float f) {
    unsigned int u = __float_as_uint(f);
    u = (u + 0x7fffu + ((u >> 16) & 1u)) >> 16;
    return (unsigned short)u;
}

__device__ __forceinline__ float gelu_f(float x) {
    const float c = 0.7978845608028654f; // sqrt(2/pi)
    float x3 = x * x * x;
    return 0.5f * x * (1.0f + tanhf(c * (x + 0.044715f * x3)));
}

// async global->LDS, 16B per lane; lds dest must be wave-uniform base + lane*16
__device__ __forceinline__ void load_lds16(const unsigned short* g, unsigned short* l) {
    __builtin_amdgcn_global_load_lds(
        (const __attribute__((address_space(1))) unsigned int*)g,
        (__attribute__((address_space(3))) unsigned int*)l,
        16, 0, 0);
}

// ---------------------------------------------------------------------------
// Per-layer weight prep: 6 transposes (fp32 [K][N] -> bf16 [N][K]) + qkv bias
// concat, one launch.
// ---------------------------------------------------------------------------
__global__ __launch_bounds__(256) void prep_layer(
    const float* __restrict__ Wq, const float* __restrict__ Wk,
    const float* __restrict__ Wv, const float* __restrict__ Wo,
    const float* __restrict__ W1, const float* __restrict__ W2,
    const float* __restrict__ bq, const float* __restrict__ bk,
    const float* __restrict__ bv,
    unsigned short* __restrict__ WqkvT, unsigned short* __restrict__ WoT,
    unsigned short* __restrict__ W1T, unsigned short* __restrict__ W2T,
    float* __restrict__ biasc)
{
    __shared__ float t[64][65];
    const int tid = threadIdx.x;
    const int id = blockIdx.x;

    if (id >= 1728) {
        int i = (id - 1728) * 256 + tid;
        if (i < 3 * H_) biasc[i] = (i < H_) ? bq[i] : (i < 2 * H_ ? bk[i - H_] : bv[i - 2 * H_]);
        return;
    }

    const float* src; unsigned short* dst; int K, N, bx, by;
    if (id < 576) {
        int wsel = id / 144, tt = id % 144;
        bx = tt % 12; by = tt / 12; K = H_; N = H_;
        src = (wsel == 0) ? Wq : (wsel == 1) ? Wk : (wsel == 2) ? Wv : Wo;
        dst = (wsel < 3) ? (WqkvT + (size_t)wsel * H_ * H_) : WoT;
    } else if (id < 1152) {
        int tt = id - 576; bx = tt % 48; by = tt / 48; K = H_; N = DFF_; src = W1; dst = W1T;
    } else {
        int tt = id - 1152; bx = tt % 12; by = tt / 12; K = DFF_; N = H_; src = W2; dst = W2T;
    }

    const int n0 = bx * 64, k0 = by * 64;
    #pragma unroll
    for (int p = 0; p < 16; ++p) {
        int idx = p * 256 + tid;
        int i = idx >> 6, j = idx & 63;
        t[i][j] = src[(size_t)(k0 + i) * N + n0 + j];
    }
    __syncthreads();
    #pragma unroll
    for (int p = 0; p < 4; ++p) {
        int q = p * 256 + tid;
        int n = q >> 4, kq = q & 15;
        unsigned int w0 = (unsigned int)f2bf(t[kq * 4 + 0][n]) | ((unsigned int)f2bf(t[kq * 4 + 1][n]) << 16);
        unsigned int w1 = (unsigned int)f2bf(t[kq * 4 + 2][n]) | ((unsigned int)f2bf(t[kq * 4 + 3][n]) << 16);
        uint2 w; w.x = w0; w.y = w1;
        *(uint2*)(dst + (size_t)(n0 + n) * K + k0 + kq * 4) = w;
    }
}

// ---------------------------------------------------------------------------
// bf16 MFMA GEMM with async global->LDS staging (m97 structure).
// EPI: 1 gelu->bf16, 2 +res fp32, 3 QKV split: Q,K bf16 rows + V transposed
// per head into Vt[bh][d][s].
// ---------------------------------------------------------------------------
template <int EPI>
__global__ __launch_bounds__(256) void gemm_bf16(
    const unsigned short* __restrict__ A,   // [M][K] bf16
    const unsigned short* __restrict__ Bt,  // [N][K] bf16
    const float* __restrict__ bias,         // [N]
    const float* __restrict__ R,            // [M][N] residual (EPI==2)
    float* __restrict__ Cf,                 // fp32 out (EPI 2)
    unsigned short* __restrict__ Cb,        // bf16 out (EPI 1,3)
    unsigned short* __restrict__ Vt,        // V^T out (EPI 3)
    int M, int N, int K)
{
    __shared__ __align__(16) unsigned short As[128 * 32];
    __shared__ __align__(16) unsigned short Bs[128 * 32];
    const int tid  = threadIdx.x;
    const int lane = tid & 63;
    const int wave = tid >> 6;
    const int wm = wave >> 1, wn = wave & 1;
    const int mbase = blockIdx.y * 128;
    const int nbase = blockIdx.x * 128;

    f32x4 acc[4][4];
    #pragma unroll
    for (int mi = 0; mi < 4; ++mi)
        #pragma unroll
        for (int ni = 0; ni < 4; ++ni) acc[mi][ni] = (f32x4){0.f, 0.f, 0.f, 0.f};

    const int crow = tid >> 2;           // 0..63
    const int kc   = tid & 3;            // 16B chunk within 32-elem k-slab
    const unsigned short* ag0 = A  + (size_t)(mbase + crow) * K + kc * 8;
    const unsigned short* ag1 = A  + (size_t)(mbase + 64 + crow) * K + kc * 8;
    const unsigned short* bg0 = Bt + (size_t)(nbase + crow) * K + kc * 8;
    const unsigned short* bg1 = Bt + (size_t)(nbase + 64 + crow) * K + kc * 8;
    unsigned short* la0 = As + (size_t)tid * 8;
    unsigned short* la1 = As + (size_t)(256 + tid) * 8;
    unsigned short* lb0 = Bs + (size_t)tid * 8;
    unsigned short* lb1 = Bs + (size_t)(256 + tid) * 8;

    const int fr = lane & 15;
    const int fc = lane >> 4;

    for (int kk = 0; kk < K; kk += 32) {
        load_lds16(ag0 + kk, la0);
        load_lds16(ag1 + kk, la1);
        load_lds16(bg0 + kk, lb0);
        load_lds16(bg1 + kk, lb1);
        __syncthreads();

        bf16x8 af[4], bf[4];
        #pragma unroll
        for (int mi = 0; mi < 4; ++mi)
            af[mi] = *(const bf16x8*)&As[(size_t)(wm * 64 + mi * 16 + fr) * 32 + fc * 8];
        #pragma unroll
        for (int ni = 0; ni < 4; ++ni)
            bf[ni] = *(const bf16x8*)&Bs[(size_t)(wn * 64 + ni * 16 + fr) * 32 + fc * 8];

        #pragma unroll
        for (int mi = 0; mi < 4; ++mi)
            #pragma unroll
            for (int ni = 0; ni < 4; ++ni)
                acc[mi][ni] = __builtin_amdgcn_mfma_f32_16x16x32_bf16(
                    af[mi], bf[ni], acc[mi][ni], 0, 0, 0);
        __syncthreads();
    }

    const int r0 = (lane >> 4) * 4;
    const int c0 = lane & 15;
    #pragma unroll
    for (int mi = 0; mi < 4; ++mi) {
        const int gm = mbase + wm * 64 + mi * 16 + r0;
        #pragma unroll
        for (int ni = 0; ni < 4; ++ni) {
            const int gn = nbase + wn * 64 + ni * 16 + c0;
            const float bv = bias[gn];
            #pragma unroll
            for (int r = 0; r < 4; ++r) {
                float vv = acc[mi][ni][r] + bv;
                const size_t off = (size_t)(gm + r) * N + gn;
                if (EPI == 1) Cb[off] = f2bf(gelu_f(vv));
                else if (EPI == 2) Cf[off] = vv + R[off];
                else { // EPI == 3 (QKV)
                    unsigned short v16 = f2bf(vv);
                    if (gn < 2 * H_) {
                        Cb[off] = v16;
                    } else {
                        int tok = gm + r;
                        Vt[(((size_t)(tok >> 9) * NHD_ + ((gn - 2 * H_) >> 6)) * DH_
                            + (gn & 63)) * S_ + (tok & (S_ - 1))] = v16;
                    }
                }
            }
        }
    }
}

// ---------------------------------------------------------------------------
// MFMA flash attention. Block = 4 waves x 16 q-rows = 64 q-rows of one head.
// Swapped QK^T (C[key][q]) -> in-lane row softmax (2 shfl_xor); P->LDS bf16;
// PV = mfma(P, V^T). K/Vt staged via global_load_lds with both-sides XOR
// swizzle (byte ^= (row&7)<<4) to kill 128B-row bank conflicts.
// ---------------------------------------------------------------------------
__global__ __launch_bounds__(256) void attn3(
    const unsigned short* __restrict__ qkvb,  // [M][2304] bf16 (Q:0-767 K:768-1535)
    const unsigned short* __restrict__ vtb,   // [B*NH][DH][S] bf16 (V^T per head)
    const int* __restrict__ mask,
    unsigned short* __restrict__ ctxb)        // [M][768] bf16
{
    const int qt = blockIdx.x, h = blockIdx.y, b = blockIdx.z;
    const int tid = threadIdx.x;
    const int lane = tid & 63;
    const int w  = tid >> 6;       // wave: q strip w*16
    const int fr = lane & 15;
    const int fh = lane >> 4;      // 0..3
    const int bh = b * NHD_ + h;

    __shared__ __align__(16) unsigned short Ks[64 * 64];
    __shared__ __align__(16) unsigned short Vts[64 * 64];
    __shared__ __align__(16) unsigned short Ps[4][16][72];   // +8 pad
    __shared__ float Ms[64];

    // persistent Q fragments: row w*16+fr, d chunks (A/B frag layout: fr=row, fh=8-chunk)
    const size_t qrow = (size_t)((b << 9) + (qt << 6) + (w << 4) + fr) * 2304 + (h << 6);
    const bf16x8 qf0 = *(const bf16x8*)&qkvb[qrow + fh * 8];
    const bf16x8 qf1 = *(const bf16x8*)&qkvb[qrow + 32 + fh * 8];

    float m = -1e30f, l = 0.f;
    f32x4 po[4];
    #pragma unroll
    for (int dg = 0; dg < 4; ++dg) po[dg] = (f32x4){0.f, 0.f, 0.f, 0.f};

    const int swz = (fr & 7) << 4;   // read-side XOR (byte units, bits 4-6)

    for (int kt = 0; kt < 8; ++kt) {
        const int kb = kt << 6;
        __syncthreads();
        {   // stage K tile and Vt tile (pre-swizzled source -> linear LDS)
            int i0 = tid, i1 = tid + 256;
            int r0s = i0 >> 3, r1s = i1 >> 3;
            int c0 = ((i0 & 7) << 4) ^ ((r0s & 7) << 4);
            int c1 = ((i1 & 7) << 4) ^ ((r1s & 7) << 4);
            load_lds16(qkvb + (size_t)((b << 9) + kb + r0s) * 2304 + H_ + (h << 6) + (c0 >> 1), Ks + i0 * 8);
            load_lds16(qkvb + (size_t)((b << 9) + kb + r1s) * 2304 + H_ + (h << 6) + (c1 >> 1), Ks + i1 * 8);
            load_lds16(vtb + ((size_t)(bh << 6) + r0s) * S_ + kb + (c0 >> 1), Vts + i0 * 8);
            load_lds16(vtb + ((size_t)(bh << 6) + r1s) * S_ + kb + (c1 >> 1), Vts + i1 * 8);
        }
        if (tid < 64) Ms[tid] = (1.0f - (float)mask[(b << 9) + kb + tid]) * -1e9f;
        __syncthreads();

        // QK^T swapped: C[key][q]; lane holds q=fr's scores for keys 16g+4*fh+r
        f32x4 sc4[4];
        #pragma unroll
        for (int g = 0; g < 4; ++g) sc4[g] = (f32x4){0.f, 0.f, 0.f, 0.f};
        #pragma unroll
        for (int c = 0; c < 2; ++c) {
            const bf16x8 qf = c ? qf1 : qf0;
            #pragma unroll
            for (int g = 0; g < 4; ++g) {
                bf16x8 kf = *(const bf16x8*)&Ks[((g << 4) + fr) * 64
                              + ((((c << 6) + (fh << 4)) ^ swz) >> 1)];
                sc4[g] = __builtin_amdgcn_mfma_f32_16x16x32_bf16(kf, qf, sc4[g], 0, 0, 0);
            }
        }

        // online softmax (all in-register; row spread over lane^16, lane^32)
        float sv[16];
        float pm = -3e38f;
        #pragma unroll
        for (int g = 0; g < 4; ++g)
            #pragma unroll
            for (int r = 0; r < 4; ++r) {
                float xx = sc4[g][r] * 0.125f + Ms[(g << 4) + (fh << 2) + r];
                sv[g * 4 + r] = xx;
                pm = fmaxf(pm, xx);
            }
        pm = fmaxf(pm, __shfl_xor(pm, 16));
        pm = fmaxf(pm, __shfl_xor(pm, 32));
        const float mnew = fmaxf(m, pm);
        const float alpha = __expf(m - mnew);
        float ps = 0.f;
        #pragma unroll
        for (int i = 0; i < 16; ++i) { sv[i] = __expf(sv[i] - mnew); ps += sv[i]; }
        ps += __shfl_xor(ps, 16);
        ps += __shfl_xor(ps, 32);
        l = l * alpha + ps;
        m = mnew;

        // P -> LDS bf16 (packed u32 writes; keys 4fh+16g+{0,1},{2,3} adjacent)
        #pragma unroll
        for (int g = 0; g < 4; ++g) {
            unsigned int* pw = (unsigned int*)&Ps[w][fr][(g << 4) + (fh << 2)];
            pw[0] = (unsigned int)f2bf(sv[g * 4 + 0]) | ((unsigned int)f2bf(sv[g * 4 + 1]) << 16);
            pw[1] = (unsigned int)f2bf(sv[g * 4 + 2]) | ((unsigned int)f2bf(sv[g * 4 + 3]) << 16);
        }

        // rescale O (alpha redistributed from softmax layout to O layout)
        float al[4];
        #pragma unroll
        for (int r = 0; r < 4; ++r) al[r] = __shfl(alpha, (fh << 2) + r);
        #pragma unroll
        for (int dg = 0; dg < 4; ++dg) {
            po[dg][0] *= al[0]; po[dg][1] *= al[1];
            po[dg][2] *= al[2]; po[dg][3] *= al[3];
        }

        // PV: C[q][d] += P[q][key] V[key][d]; A=P rows, Bt=Vt rows
        const bf16x8 pf0 = *(const bf16x8*)&Ps[w][fr][fh * 8];
        const bf16x8 pf1 = *(const bf16x8*)&Ps[w][fr][32 + fh * 8];
        #pragma unroll
        for (int dg = 0; dg < 4; ++dg) {
            bf16x8 vf0 = *(const bf16x8*)&Vts[((dg << 4) + fr) * 64 + (((fh << 4) ^ swz) >> 1)];
            po[dg] = __builtin_amdgcn_mfma_f32_16x16x32_bf16(pf0, vf0, po[dg], 0, 0, 0);
            bf16x8 vf1 = *(const bf16x8*)&Vts[((dg << 4) + fr) * 64 + (((64 + (fh << 4)) ^ swz) >> 1)];
            po[dg] = __builtin_amdgcn_mfma_f32_16x16x32_bf16(pf1, vf1, po[dg], 0, 0, 0);
        }
    }

    float inv[4];
    #pragma unroll
    for (int r = 0; r < 4; ++r) inv[r] = 1.0f / __shfl(l, (fh << 2) + r);
    #pragma unroll
    for (int r = 0; r < 4; ++r) {
        unsigned short* op = ctxb
            + (size_t)((b << 9) + (qt << 6) + (w << 4) + (fh << 2) + r) * H_
            + (h << 6) + fr;
        #pragma unroll
        for (int dg = 0; dg < 4; ++dg)
            op[dg << 4] = f2bf(po[dg][r] * inv[r]);
    }
}

// ---------------------------------------------------------------------------
// Row LayerNorm; writes fp32 + bf16 copies.
// ---------------------------------------------------------------------------
__global__ __launch_bounds__(256) void ln_kernel(
    const float* __restrict__ in, const float* __restrict__ sc,
    const float* __restrict__ bi, float* __restrict__ out,
    unsigned short* __restrict__ outb)
{
    const int row = blockIdx.x;
    const int tid = threadIdx.x;
    const float* x = in + (size_t)row * H_;
    float v[3], s0 = 0.f, s1 = 0.f;
    #pragma unroll
    for (int r = 0; r < 3; ++r) {
        v[r] = x[tid + r * 256];
        s0 += v[r]; s1 += v[r] * v[r];
    }
    __shared__ float red[8];
    __shared__ float stat[2];
    #pragma unroll
    for (int o = 32; o > 0; o >>= 1) { s0 += __shfl_down(s0, o); s1 += __shfl_down(s1, o); }
    if ((tid & 63) == 0) { red[tid >> 6] = s0; red[4 + (tid >> 6)] = s1; }
    __syncthreads();
    if (tid == 0) {
        float t0 = red[0] + red[1] + red[2] + red[3];
        float t1 = red[4] + red[5] + red[6] + red[7];
        float mean = t0 / H_;
        float var  = t1 / H_ - mean * mean;
        stat[0] = mean;
        stat[1] = rsqrtf(var + 1e-12f);
    }
    __syncthreads();
    float mean = stat[0], rstd = stat[1];
    float* o = out + (size_t)row * H_;
    unsigned short* ob = outb + (size_t)row * H_;
    #pragma unroll
    for (int r = 0; r < 3; ++r) {
        int i = tid + r * 256;
        float rr = (v[r] - mean) * rstd * sc[i] + bi[i];
        o[i] = rr;
        ob[i] = f2bf(rr);
    }
}

__global__ __launch_bounds__(256) void embed_ln_kernel(
    const int* __restrict__ ids, const float* __restrict__ tok,
    const float* __restrict__ pos, const float* __restrict__ sc,
    const float* __restrict__ bi, float* __restrict__ out,
    unsigned short* __restrict__ outb)
{
    const int row = blockIdx.x;
    const int spos = row & (S_ - 1);
    const int tid = threadIdx.x;
    const int id = ids[row];
    const float* t = tok + (size_t)id * H_;
    const float* p = pos + (size_t)spos * H_;
    float v[3], s0 = 0.f, s1 = 0.f;
    #pragma unroll
    for (int r = 0; r < 3; ++r) {
        int i = tid + r * 256;
        v[r] = t[i] + p[i];
        s0 += v[r]; s1 += v[r] * v[r];
    }
    __shared__ float red[8];
    __shared__ float stat[2];
    #pragma unroll
    for (int o = 32; o > 0; o >>= 1) { s0 += __shfl_down(s0, o); s1 += __shfl_down(s1, o); }
    if ((tid & 63) == 0) { red[tid >> 6] = s0; red[4 + (tid >> 6)] = s1; }
    __syncthreads();
    if (tid == 0) {
        float t0 = red[0] + red[1] + red[2] + red[3];
        float t1 = red[4] + red[5] + red[6] + red[7];
        float mean = t0 / H_;
        float var  = t1 / H_ - mean * mean;
        stat[0] = mean;
        stat[1] = rsqrtf(var + 1e-12f);
    }
    __syncthreads();
    float mean = stat[0], rstd = stat[1];
    float* o = out + (size_t)row * H_;
    unsigned short* ob = outb + (size_t)row * H_;
    #pragma unroll
    for (int r = 0; r < 3; ++r) {
        int i = tid + r * 256;
        float rr = (v[r] - mean) * rstd * sc[i] + bi[i];
        o[i] = rr;
        ob[i] = f2bf(rr);
    }
}

// ---------------------------------------------------------------------------
// Classifier SIMT GEMM (N=19, tiny) — fp32.
// ---------------------------------------------------------------------------
__global__ __launch_bounds__(256) void gemm_cls(
    const float* __restrict__ A, const float* __restrict__ W,
    const float* __restrict__ bias, float* __restrict__ C, int M, int N, int K)
{
    __shared__ float As[16][65];
    __shared__ float Ws[16][64];
    const int tid = threadIdx.x;
    const int tx = tid & 15;
    const int ty = tid >> 4;
    const int mbase = blockIdx.y * 64;
    const int nbase = blockIdx.x * 64;
    float acc[4][4] = {};
    for (int kk = 0; kk < K; kk += 16) {
        #pragma unroll
        for (int r = 0; r < 4; ++r) {
            int idx = r * 256 + tid;
            int mm = idx >> 4, k4 = idx & 15;
            As[k4][mm] = A[(size_t)(mbase + mm) * K + kk + k4];
        }
        #pragma unroll
        for (int r = 0; r < 4; ++r) {
            int idx = r * 256 + tid;
            int n = idx & 63, k4 = idx >> 6;
            int gn = nbase + n;
            Ws[k4][n] = (gn < N) ? W[(size_t)(kk + k4) * N + gn] : 0.0f;
        }
        __syncthreads();
        #pragma unroll
        for (int k = 0; k < 16; ++k) {
            float a[4], w[4];
            #pragma unroll
            for (int i = 0; i < 4; ++i) a[i] = As[k][ty * 4 + i];
            #pragma unroll
            for (int j = 0; j < 4; ++j) w[j] = Ws[k][tx * 4 + j];
            #pragma unroll
            for (int i = 0; i < 4; ++i)
                #pragma unroll
                for (int j = 0; j < 4; ++j)
                    acc[i][j] = fmaf(a[i], w[j], acc[i][j]);
        }
        __syncthreads();
    }
    #pragma unroll
    for (int i = 0; i < 4; ++i) {
        int gm = mbase + ty * 4 + i;
        #pragma unroll
        for (int j = 0; j < 4; ++j) {
            int gn = nbase + tx * 4 + j;
            if (gn < N) C[(size_t)gm * N + gn] = acc[i][j] + bias[gn];
        }
    }
}

// ---------------------------------------------------------------------------
// CRF numerator per batch
// ---------------------------------------------------------------------------
__global__ __launch_bounds__(256) void crf_num_kernel(
    const float* __restrict__ logits, const int* __restrict__ labels,
    const int* __restrict__ mask, const float* __restrict__ start_trans,
    const float* __restrict__ end_trans, const float* __restrict__ trans,
    float* __restrict__ numb)
{
    const int b = blockIdx.x;
    const int tid = threadIdx.x;
    float lsum = 0.f, lmask = 0.f;
    for (int t = tid; t < S_; t += 256) {
        float mf = (float)mask[b * S_ + t];
        lmask += mf;
        if (t >= 1) {
            int lp = labels[b * S_ + t - 1];
            int lc = labels[b * S_ + t];
            float em = logits[((size_t)b * S_ + t) * NL_ + lc];
            lsum += (trans[lp * NL_ + lc] + em) * mf;
        }
    }
    __shared__ float red[8];
    #pragma unroll
    for (int o = 32; o > 0; o >>= 1) { lsum += __shfl_down(lsum, o); lmask += __shfl_down(lmask, o); }
    if ((tid & 63) == 0) { red[tid >> 6] = lsum; red[4 + (tid >> 6)] = lmask; }
    __syncthreads();
    if (tid == 0) {
        float ts = red[0] + red[1] + red[2] + red[3];
        float tm = red[4] + red[5] + red[6] + red[7];
        int l0 = labels[b * S_];
        float nm = start_trans[l0] + logits[(size_t)b * S_ * NL_ + l0] + ts;
        int last = (int)tm - 1;
        int lt = labels[b * S_ + last];
        nm += end_trans[lt];
        numb[b] = nm;
    }
}

// ---------------------------------------------------------------------------
// CRF forward, parallel scan in log-semiring (chunk + tree combine).
// ---------------------------------------------------------------------------
__global__ __launch_bounds__(384) void crf_chunk_kernel(
    const float* __restrict__ logits, const int* __restrict__ mask,
    const float* __restrict__ trans, float* __restrict__ Pg)
{
    const int c = blockIdx.x, b = blockIdx.y;
    const int tid = threadIdx.x;
    const bool act = tid < NL_ * NL_;
    const int i = tid / NL_;
    const int j = tid - i * NL_;

    const int t0 = 1 + c * CHL_;
    const int nt = min(CHL_, S_ - t0);

    __shared__ float P[NL_][20];
    __shared__ float tr_s[NL_ * NL_];
    __shared__ float em_s[CHL_ * NL_];
    __shared__ int mk[CHL_];

    for (int f = tid; f < NL_ * NL_; f += 384) tr_s[f] = trans[f];
    for (int f = tid; f < nt * NL_; f += 384)
        em_s[f] = logits[((size_t)b * S_ + t0) * NL_ + f];
    if (tid < nt) mk[tid] = mask[b * S_ + t0 + tid];
    __syncthreads();

    float trcol[NL_];
    if (act) {
        #pragma unroll
        for (int k = 0; k < NL_; ++k) trcol[k] = tr_s[k * NL_ + j];
        float p0;
        if (mk[0] > 0) p0 = tr_s[i * NL_ + j] + em_s[j];
        else           p0 = (i == j) ? 0.f : -1e30f;
        P[i][j] = p0;
    }
    __syncthreads();

    for (int tt = 1; tt < nt; ++tt) {
        float nv = 0.f;
        if (act) {
            float v[NL_];
            float vmax = -3e38f;
            #pragma unroll
            for (int k = 0; k < NL_; ++k) {
                v[k] = P[i][k] + trcol[k];
                vmax = fmaxf(vmax, v[k]);
            }
            float s = 0.f;
            #pragma unroll
            for (int k = 0; k < NL_; ++k) s += __expf(v[k] - vmax);
            nv = vmax + __logf(s) + em_s[tt * NL_ + j];
        }
        __syncthreads();
        if (act && mk[tt] > 0) P[i][j] = nv;
        __syncthreads();
    }

    if (act) Pg[((size_t)b * NCH_ + c) * (NL_ * NL_) + tid] = P[i][j];
}

__global__ __launch_bounds__(384) void crf_combine_kernel(
    const float* __restrict__ Pg, const float* __restrict__ logits,
    const float* __restrict__ start_trans, const float* __restrict__ end_trans,
    float* __restrict__ denb)
{
    const int b = blockIdx.x;
    const int tid = threadIdx.x;
    __shared__ float Q[NCH_ * NL_ * NL_];
    __shared__ float fin[NL_];

    for (int w = tid; w < NCH_ * NL_ * NL_; w += 384)
        Q[w] = Pg[(size_t)b * NCH_ * NL_ * NL_ + w];
    __syncthreads();

    for (int m = NCH_ / 2; m >= 1; m >>= 1) {
        const int items = m * NL_ * NL_;
        float res[16];
        #pragma unroll
        for (int r = 0; r < 16; ++r) {
            const int w = tid + r * 384;
            if (w < items) {
                const int p = w / (NL_ * NL_);
                const int e = w - p * (NL_ * NL_);
                const int ii = e / NL_;
                const int jj = e - ii * NL_;
                const float* Lm = &Q[(2 * p) * NL_ * NL_ + ii * NL_];
                const float* Rm = &Q[(2 * p + 1) * NL_ * NL_ + jj];
                float v[NL_];
                float vmax = -3e38f;
                #pragma unroll
                for (int k = 0; k < NL_; ++k) {
                    v[k] = Lm[k] + Rm[k * NL_];
                    vmax = fmaxf(vmax, v[k]);
                }
                float s = 0.f;
                #pragma unroll
                for (int k = 0; k < NL_; ++k) s += __expf(v[k] - vmax);
                res[r] = vmax + __logf(s);
            }
        }
        __syncthreads();
        #pragma unroll
        for (int r = 0; r < 16; ++r) {
            const int w = tid + r * 384;
            if (w < items) Q[w] = res[r];
        }
        __syncthreads();
    }

    if (tid < NL_) {
        float v[NL_];
        float vmax = -3e38f;
        #pragma unroll
        for (int k = 0; k < NL_; ++k) {
            v[k] = start_trans[k] + logits[(size_t)b * S_ * NL_ + k] + Q[k * NL_ + tid];
            vmax = fmaxf(vmax, v[k]);
        }
        float s = 0.f;
        #pragma unroll
        for (int k = 0; k < NL_; ++k) s += __expf(v[k] - vmax);
        fin[tid] = vmax + __logf(s) + end_trans[tid];
    }
    __syncthreads();
    if (tid == 0) {
        float vmax = -3e38f;
        #pragma unroll
        for (int k = 0; k < NL_; ++k) vmax = fmaxf(vmax, fin[k]);
        float s = 0.f;
        #pragma unroll
        for (int k = 0; k < NL_; ++k) s += __expf(fin[k] - vmax);
        denb[b] = vmax + __logf(s);
    }
}

__global__ void finalize_kernel(const float* __restrict__ numb,
                                const float* __restrict__ denb,
                                float* __restrict__ out)
{
    if (threadIdx.x == 0 && blockIdx.x == 0) {
        float s = 0.f;
        for (int b = 0; b < B_; ++b) s += denb[b] - numb[b];
        out[0] = s;
    }
}

// ---------------------------------------------------------------------------
extern "C" void kernel_launch(void* const* d_in, const int* in_sizes, int n_in,
                              void* d_out, int out_size, void* d_ws, size_t ws_size,
                              hipStream_t stream)
{
    const int*   input_ids = (const int*)d_in[0];
    const int*   attn_mask = (const int*)d_in[1];
    const int*   labels    = (const int*)d_in[2];
    const float* token_emb = (const float*)d_in[3];
    const float* pos_emb   = (const float*)d_in[4];
    const float* ln_emb_s  = (const float*)d_in[5];
    const float* ln_emb_b  = (const float*)d_in[6];
    const float* Wq  = (const float*)d_in[7];
    const float* bq  = (const float*)d_in[8];
    const float* Wk  = (const float*)d_in[9];
    const float* bk  = (const float*)d_in[10];
    const float* Wv  = (const float*)d_in[11];
    const float* bv  = (const float*)d_in[12];
    const float* Wo  = (const float*)d_in[13];
    const float* bo  = (const float*)d_in[14];
    const float* ln1s = (const float*)d_in[15];
    const float* ln1b = (const float*)d_in[16];
    const float* W1  = (const float*)d_in[17];
    const float* b1  = (const float*)d_in[18];
    const float* W2  = (const float*)d_in[19];
    const float* b2  = (const float*)d_in[20];
    const float* ln2s = (const float*)d_in[21];
    const float* ln2b = (const float*)d_in[22];
    const float* cls_W = (const float*)d_in[23];
    const float* cls_b = (const float*)d_in[24];
    const float* start_trans = (const float*)d_in[25];
    const float* end_trans   = (const float*)d_in[26];
    const float* trans       = (const float*)d_in[27];

    char* base = (char*)d_ws;
    const int M = B_ * S_;                                  // 4096
    // region0 (25.17 MB): qkvb[M][2304] + vtb[96][64][512] bf16 during attn,
    // aliased by hbb[M][3072] bf16 during FFN (disjoint lifetimes; same size).
    unsigned short* qkvb = (unsigned short*)base;
    unsigned short* vtb  = qkvb + (size_t)M * 2304;
    unsigned short* hbb  = (unsigned short*)base;
    size_t off = (size_t)M * 3072 * 2;
    float*          x     = (float*)(base + off); off += (size_t)M * H_ * 4;
    float*          y     = (float*)(base + off); off += (size_t)M * H_ * 4;
    unsigned short* xb    = (unsigned short*)(base + off); off += (size_t)M * H_ * 2;
    unsigned short* ctxb  = (unsigned short*)(base + off); off += (size_t)M * H_ * 2;
    unsigned short* WqkvT = (unsigned short*)(base + off); off += (size_t)3 * H_ * H_ * 2;
    unsigned short* WoT   = (unsigned short*)(base + off); off += (size_t)H_ * H_ * 2;
    unsigned short* W1T   = (unsigned short*)(base + off); off += (size_t)DFF_ * H_ * 2;
    unsigned short* W2T   = (unsigned short*)(base + off); off += (size_t)H_ * DFF_ * 2;
    float*          biasc = (float*)(base + off); off += 3 * H_ * 4 + 256;
    float*          logits= (float*)(base + off); off += (size_t)M * NL_ * 4;
    float*          numb  = (float*)(base + off); off += 32;
    float*          denb  = (float*)(base + off); off += 32;
    float*          Pg    = (float*)(base + off); off += (size_t)B_ * NCH_ * NL_ * NL_ * 4;

    dim3 blk(256);
    embed_ln_kernel<<<M, blk, 0, stream>>>(input_ids, token_emb, pos_emb, ln_emb_s, ln_emb_b, x, xb);

    for (int l = 0; l < L_; ++l) {
        const size_t oHH = (size_t)l * H_ * H_;
        const size_t oHF = (size_t)l * H_ * DFF_;
        prep_layer<<<1737, blk, 0, stream>>>(
            Wq + oHH, Wk + oHH, Wv + oHH, Wo + oHH, W1 + oHF, W2 + oHF,
            bq + l * H_, bk + l * H_, bv + l * H_,
            WqkvT, WoT, W1T, W2T, biasc);

        gemm_bf16<3><<<dim3(18, 32), blk, 0, stream>>>(xb, WqkvT, biasc, nullptr, nullptr, qkvb, vtb, M, 3 * H_, H_);
        attn3<<<dim3(8, NHD_, B_), blk, 0, stream>>>(qkvb, vtb, attn_mask, ctxb);
        gemm_bf16<2><<<dim3(6, 32), blk, 0, stream>>>(ctxb, WoT, bo + l * H_, x, y, nullptr, nullptr, M, H_, H_);
        ln_kernel<<<M, blk, 0, stream>>>(y, ln1s + l * H_, ln1b + l * H_, x, xb);
        gemm_bf16<1><<<dim3(24, 32), blk, 0, stream>>>(xb, W1T, b1 + l * DFF_, nullptr, nullptr, hbb, nullptr, M, DFF_, H_);
        gemm_bf16<2><<<dim3(6, 32), blk, 0, stream>>>(hbb, W2T, b2 + l * H_, x, y, nullptr, nullptr, M, H_, DFF_);
        ln_kernel<<<M, blk, 0, stream>>>(y, ln2s + l * H_, ln2b + l * H_, x, xb);
    }

    gemm_cls<<<dim3(1, M / 64), blk, 0, stream>>>(x, cls_W, cls_b, logits, M, NL_, H_);
    crf_num_kernel<<<B_, blk, 0, stream>>>(logits, labels, attn_mask, start_trans, end_trans, trans, numb);
    crf_chunk_kernel<<<dim3(NCH_, B_), dim3(384), 0, stream>>>(logits, attn_mask, trans, Pg);
    crf_combine_kernel<<<B_, dim3(384), 0, stream>>>(Pg, logits, start_trans, end_trans, denb);
    finalize_kernel<<<1, 64, 0, stream>>>(numb, denb, (float*)d_out);
}

// Round 3
// 2916.656 us; speedup vs baseline: 1.6563x; 1.0838x over previous
//
#include <hip/hip_runtime.h>
#include <hip/hip_bf16.h>
#include <math.h>

#define B_   8
#define S_   512
#define H_   768
#define L_   12
#define NHD_ 12
#define DH_  64
#define DFF_ 3072
#define NL_  19

#define NCH_ 32   // CRF chunks per batch
#define CHL_ 16   // timesteps per chunk (last chunk has 15)

typedef __bf16 bf16x8 __attribute__((ext_vector_type(8)));
typedef float  f32x4  __attribute__((ext_vector_type(4)));

__device__ __forceinline__ unsigned short f2bf(float f) {
    unsigned int u = __float_as_uint(f);
    u = (u + 0x7fffu + ((u >> 16) & 1u)) >> 16;
    return (unsigned short)u;
}

__device__ __forceinline__ float gelu_f(float x) {
    const float c = 0.7978845608028654f; // sqrt(2/pi)
    float x3 = x * x * x;
    return 0.5f * x * (1.0f + tanhf(c * (x + 0.044715f * x3)));
}

// async global->LDS, 16B per lane; lds dest must be wave-uniform base + lane*16
__device__ __forceinline__ void load_lds16(const unsigned short* g, unsigned short* l) {
    __builtin_amdgcn_global_load_lds(
        (const __attribute__((address_space(1))) unsigned int*)g,
        (__attribute__((address_space(3))) unsigned int*)l,
        16, 0, 0);
}

// ---------------------------------------------------------------------------
// Per-layer weight prep: 6 transposes (fp32 [K][N] -> bf16 [N][K]) + qkv bias
// concat, one launch.
// ---------------------------------------------------------------------------
__global__ __launch_bounds__(256) void prep_layer(
    const float* __restrict__ Wq, const float* __restrict__ Wk,
    const float* __restrict__ Wv, const float* __restrict__ Wo,
    const float* __restrict__ W1, const float* __restrict__ W2,
    const float* __restrict__ bq, const float* __restrict__ bk,
    const float* __restrict__ bv,
    unsigned short* __restrict__ WqkvT, unsigned short* __restrict__ WoT,
    unsigned short* __restrict__ W1T, unsigned short* __restrict__ W2T,
    float* __restrict__ biasc)
{
    __shared__ float t[64][65];
    const int tid = threadIdx.x;
    const int id = blockIdx.x;

    if (id >= 1728) {
        int i = (id - 1728) * 256 + tid;
        if (i < 3 * H_) biasc[i] = (i < H_) ? bq[i] : (i < 2 * H_ ? bk[i - H_] : bv[i - 2 * H_]);
        return;
    }

    const float* src; unsigned short* dst; int K, N, bx, by;
    if (id < 576) {
        int wsel = id / 144, tt = id % 144;
        bx = tt % 12; by = tt / 12; K = H_; N = H_;
        src = (wsel == 0) ? Wq : (wsel == 1) ? Wk : (wsel == 2) ? Wv : Wo;
        dst = (wsel < 3) ? (WqkvT + (size_t)wsel * H_ * H_) : WoT;
    } else if (id < 1152) {
        int tt = id - 576; bx = tt % 48; by = tt / 48; K = H_; N = DFF_; src = W1; dst = W1T;
    } else {
        int tt = id - 1152; bx = tt % 12; by = tt / 12; K = DFF_; N = H_; src = W2; dst = W2T;
    }

    const int n0 = bx * 64, k0 = by * 64;
    #pragma unroll
    for (int p = 0; p < 16; ++p) {
        int idx = p * 256 + tid;
        int i = idx >> 6, j = idx & 63;
        t[i][j] = src[(size_t)(k0 + i) * N + n0 + j];
    }
    __syncthreads();
    #pragma unroll
    for (int p = 0; p < 4; ++p) {
        int q = p * 256 + tid;
        int n = q >> 4, kq = q & 15;
        unsigned int w0 = (unsigned int)f2bf(t[kq * 4 + 0][n]) | ((unsigned int)f2bf(t[kq * 4 + 1][n]) << 16);
        unsigned int w1 = (unsigned int)f2bf(t[kq * 4 + 2][n]) | ((unsigned int)f2bf(t[kq * 4 + 3][n]) << 16);
        uint2 w; w.x = w0; w.y = w1;
        *(uint2*)(dst + (size_t)(n0 + n) * K + k0 + kq * 4) = w;
    }
}

// ---------------------------------------------------------------------------
// bf16 MFMA GEMM, double-buffered (T3 2-phase) + XCD-aware block swizzle (T1).
// EPI: 1 gelu->bf16, 2 +res fp32, 3 QKV split (Q,K bf16 rows + V^T per head).
// Next K-slab's global_load_lds issues into buf^1 BEFORE compute of buf, so
// the vmcnt(0) drain at __syncthreads overlaps 16 MFMAs instead of stalling.
// Grids must have nwg % 8 == 0 (all call sites: 576/192/768/192).
// ---------------------------------------------------------------------------
template <int EPI>
__global__ __launch_bounds__(256) void gemm_bf16(
    const unsigned short* __restrict__ A,   // [M][K] bf16
    const unsigned short* __restrict__ Bt,  // [N][K] bf16
    const float* __restrict__ bias,         // [N]
    const float* __restrict__ R,            // [M][N] residual (EPI==2)
    float* __restrict__ Cf,                 // fp32 out (EPI 2)
    unsigned short* __restrict__ Cb,        // bf16 out (EPI 1,3)
    unsigned short* __restrict__ Vt,        // V^T out (EPI 3)
    int M, int N, int K)
{
    __shared__ __align__(16) unsigned short As[2][128 * 32];
    __shared__ __align__(16) unsigned short Bs[2][128 * 32];
    const int tid  = threadIdx.x;
    const int lane = tid & 63;
    const int wave = tid >> 6;
    const int wm = wave >> 1, wn = wave & 1;

    // XCD swizzle: contiguous grid chunk per XCD (bijective since nwg%8==0)
    const int nwg  = gridDim.x * gridDim.y;
    const int orig = blockIdx.y * gridDim.x + blockIdx.x;
    const int cpx  = nwg >> 3;
    const int sw   = (orig & 7) * cpx + (orig >> 3);
    const int mbase = (sw / gridDim.x) * 128;
    const int nbase = (sw % gridDim.x) * 128;

    f32x4 acc[4][4];
    #pragma unroll
    for (int mi = 0; mi < 4; ++mi)
        #pragma unroll
        for (int ni = 0; ni < 4; ++ni) acc[mi][ni] = (f32x4){0.f, 0.f, 0.f, 0.f};

    const int crow = tid >> 2;           // 0..63
    const int kc   = tid & 3;            // 16B chunk within 32-elem k-slab
    const unsigned short* ag0 = A  + (size_t)(mbase + crow) * K + kc * 8;
    const unsigned short* ag1 = A  + (size_t)(mbase + 64 + crow) * K + kc * 8;
    const unsigned short* bg0 = Bt + (size_t)(nbase + crow) * K + kc * 8;
    const unsigned short* bg1 = Bt + (size_t)(nbase + 64 + crow) * K + kc * 8;

    const int fr = lane & 15;
    const int fc = lane >> 4;

#define STAGE_(c, kk) do { \
        load_lds16(ag0 + (kk), As[c] + (size_t)tid * 8); \
        load_lds16(ag1 + (kk), As[c] + (size_t)(256 + tid) * 8); \
        load_lds16(bg0 + (kk), Bs[c] + (size_t)tid * 8); \
        load_lds16(bg1 + (kk), Bs[c] + (size_t)(256 + tid) * 8); \
    } while (0)

    STAGE_(0, 0);
    __syncthreads();                       // drain prologue stage

    int cur = 0;
    for (int kk = 0; kk < K; kk += 32) {
        if (kk + 32 < K) STAGE_(cur ^ 1, kk + 32);   // prefetch next slab

        bf16x8 af[4], bf4[4];
        #pragma unroll
        for (int mi = 0; mi < 4; ++mi)
            af[mi] = *(const bf16x8*)&As[cur][(size_t)(wm * 64 + mi * 16 + fr) * 32 + fc * 8];
        #pragma unroll
        for (int ni = 0; ni < 4; ++ni)
            bf4[ni] = *(const bf16x8*)&Bs[cur][(size_t)(wn * 64 + ni * 16 + fr) * 32 + fc * 8];

        #pragma unroll
        for (int mi = 0; mi < 4; ++mi)
            #pragma unroll
            for (int ni = 0; ni < 4; ++ni)
                acc[mi][ni] = __builtin_amdgcn_mfma_f32_16x16x32_bf16(
                    af[mi], bf4[ni], acc[mi][ni], 0, 0, 0);

        __syncthreads();                   // waits vmcnt(0): prefetch done; buf swap safe
        cur ^= 1;
    }
#undef STAGE_

    const int r0 = (lane >> 4) * 4;
    const int c0 = lane & 15;
    #pragma unroll
    for (int mi = 0; mi < 4; ++mi) {
        const int gm = mbase + wm * 64 + mi * 16 + r0;
        #pragma unroll
        for (int ni = 0; ni < 4; ++ni) {
            const int gn = nbase + wn * 64 + ni * 16 + c0;
            const float bv = bias[gn];
            #pragma unroll
            for (int r = 0; r < 4; ++r) {
                float vv = acc[mi][ni][r] + bv;
                const size_t off = (size_t)(gm + r) * N + gn;
                if (EPI == 1) Cb[off] = f2bf(gelu_f(vv));
                else if (EPI == 2) Cf[off] = vv + R[off];
                else { // EPI == 3 (QKV)
                    unsigned short v16 = f2bf(vv);
                    if (gn < 2 * H_) {
                        Cb[off] = v16;
                    } else {
                        int tok = gm + r;
                        Vt[(((size_t)(tok >> 9) * NHD_ + ((gn - 2 * H_) >> 6)) * DH_
                            + (gn & 63)) * S_ + (tok & (S_ - 1))] = v16;
                    }
                }
            }
        }
    }
}

// ---------------------------------------------------------------------------
// MFMA flash attention (unchanged from round 2).
// ---------------------------------------------------------------------------
__global__ __launch_bounds__(256) void attn3(
    const unsigned short* __restrict__ qkvb,  // [M][2304] bf16 (Q:0-767 K:768-1535)
    const unsigned short* __restrict__ vtb,   // [B*NH][DH][S] bf16 (V^T per head)
    const int* __restrict__ mask,
    unsigned short* __restrict__ ctxb)        // [M][768] bf16
{
    const int qt = blockIdx.x, h = blockIdx.y, b = blockIdx.z;
    const int tid = threadIdx.x;
    const int lane = tid & 63;
    const int w  = tid >> 6;       // wave: q strip w*16
    const int fr = lane & 15;
    const int fh = lane >> 4;      // 0..3
    const int bh = b * NHD_ + h;

    __shared__ __align__(16) unsigned short Ks[64 * 64];
    __shared__ __align__(16) unsigned short Vts[64 * 64];
    __shared__ __align__(16) unsigned short Ps[4][16][72];   // +8 pad
    __shared__ float Ms[64];

    const size_t qrow = (size_t)((b << 9) + (qt << 6) + (w << 4) + fr) * 2304 + (h << 6);
    const bf16x8 qf0 = *(const bf16x8*)&qkvb[qrow + fh * 8];
    const bf16x8 qf1 = *(const bf16x8*)&qkvb[qrow + 32 + fh * 8];

    float m = -1e30f, l = 0.f;
    f32x4 po[4];
    #pragma unroll
    for (int dg = 0; dg < 4; ++dg) po[dg] = (f32x4){0.f, 0.f, 0.f, 0.f};

    const int swz = (fr & 7) << 4;   // read-side XOR (byte units, bits 4-6)

    for (int kt = 0; kt < 8; ++kt) {
        const int kb = kt << 6;
        __syncthreads();
        {   // stage K tile and Vt tile (pre-swizzled source -> linear LDS)
            int i0 = tid, i1 = tid + 256;
            int r0s = i0 >> 3, r1s = i1 >> 3;
            int c0 = ((i0 & 7) << 4) ^ ((r0s & 7) << 4);
            int c1 = ((i1 & 7) << 4) ^ ((r1s & 7) << 4);
            load_lds16(qkvb + (size_t)((b << 9) + kb + r0s) * 2304 + H_ + (h << 6) + (c0 >> 1), Ks + i0 * 8);
            load_lds16(qkvb + (size_t)((b << 9) + kb + r1s) * 2304 + H_ + (h << 6) + (c1 >> 1), Ks + i1 * 8);
            load_lds16(vtb + ((size_t)(bh << 6) + r0s) * S_ + kb + (c0 >> 1), Vts + i0 * 8);
            load_lds16(vtb + ((size_t)(bh << 6) + r1s) * S_ + kb + (c1 >> 1), Vts + i1 * 8);
        }
        if (tid < 64) Ms[tid] = (1.0f - (float)mask[(b << 9) + kb + tid]) * -1e9f;
        __syncthreads();

        // QK^T swapped: C[key][q]; lane holds q=fr's scores for keys 16g+4*fh+r
        f32x4 sc4[4];
        #pragma unroll
        for (int g = 0; g < 4; ++g) sc4[g] = (f32x4){0.f, 0.f, 0.f, 0.f};
        #pragma unroll
        for (int c = 0; c < 2; ++c) {
            const bf16x8 qf = c ? qf1 : qf0;
            #pragma unroll
            for (int g = 0; g < 4; ++g) {
                bf16x8 kf = *(const bf16x8*)&Ks[((g << 4) + fr) * 64
                              + ((((c << 6) + (fh << 4)) ^ swz) >> 1)];
                sc4[g] = __builtin_amdgcn_mfma_f32_16x16x32_bf16(kf, qf, sc4[g], 0, 0, 0);
            }
        }

        // online softmax (in-register; row spread over lane^16, lane^32)
        float sv[16];
        float pm = -3e38f;
        #pragma unroll
        for (int g = 0; g < 4; ++g)
            #pragma unroll
            for (int r = 0; r < 4; ++r) {
                float xx = sc4[g][r] * 0.125f + Ms[(g << 4) + (fh << 2) + r];
                sv[g * 4 + r] = xx;
                pm = fmaxf(pm, xx);
            }
        pm = fmaxf(pm, __shfl_xor(pm, 16));
        pm = fmaxf(pm, __shfl_xor(pm, 32));
        const float mnew = fmaxf(m, pm);
        const float alpha = __expf(m - mnew);
        float ps = 0.f;
        #pragma unroll
        for (int i = 0; i < 16; ++i) { sv[i] = __expf(sv[i] - mnew); ps += sv[i]; }
        ps += __shfl_xor(ps, 16);
        ps += __shfl_xor(ps, 32);
        l = l * alpha + ps;
        m = mnew;

        // P -> LDS bf16
        #pragma unroll
        for (int g = 0; g < 4; ++g) {
            unsigned int* pw = (unsigned int*)&Ps[w][fr][(g << 4) + (fh << 2)];
            pw[0] = (unsigned int)f2bf(sv[g * 4 + 0]) | ((unsigned int)f2bf(sv[g * 4 + 1]) << 16);
            pw[1] = (unsigned int)f2bf(sv[g * 4 + 2]) | ((unsigned int)f2bf(sv[g * 4 + 3]) << 16);
        }

        // rescale O
        float al[4];
        #pragma unroll
        for (int r = 0; r < 4; ++r) al[r] = __shfl(alpha, (fh << 2) + r);
        #pragma unroll
        for (int dg = 0; dg < 4; ++dg) {
            po[dg][0] *= al[0]; po[dg][1] *= al[1];
            po[dg][2] *= al[2]; po[dg][3] *= al[3];
        }

        // PV: C[q][d] += P[q][key] V[key][d]
        const bf16x8 pf0 = *(const bf16x8*)&Ps[w][fr][fh * 8];
        const bf16x8 pf1 = *(const bf16x8*)&Ps[w][fr][32 + fh * 8];
        #pragma unroll
        for (int dg = 0; dg < 4; ++dg) {
            bf16x8 vf0 = *(const bf16x8*)&Vts[((dg << 4) + fr) * 64 + (((fh << 4) ^ swz) >> 1)];
            po[dg] = __builtin_amdgcn_mfma_f32_16x16x32_bf16(pf0, vf0, po[dg], 0, 0, 0);
            bf16x8 vf1 = *(const bf16x8*)&Vts[((dg << 4) + fr) * 64 + (((64 + (fh << 4)) ^ swz) >> 1)];
            po[dg] = __builtin_amdgcn_mfma_f32_16x16x32_bf16(pf1, vf1, po[dg], 0, 0, 0);
        }
    }

    float inv[4];
    #pragma unroll
    for (int r = 0; r < 4; ++r) inv[r] = 1.0f / __shfl(l, (fh << 2) + r);
    #pragma unroll
    for (int r = 0; r < 4; ++r) {
        unsigned short* op = ctxb
            + (size_t)((b << 9) + (qt << 6) + (w << 4) + (fh << 2) + r) * H_
            + (h << 6) + fr;
        #pragma unroll
        for (int dg = 0; dg < 4; ++dg)
            op[dg << 4] = f2bf(po[dg][r] * inv[r]);
    }
}

// ---------------------------------------------------------------------------
// Row LayerNorm; writes fp32 + bf16 copies.
// ---------------------------------------------------------------------------
__global__ __launch_bounds__(256) void ln_kernel(
    const float* __restrict__ in, const float* __restrict__ sc,
    const float* __restrict__ bi, float* __restrict__ out,
    unsigned short* __restrict__ outb)
{
    const int row = blockIdx.x;
    const int tid = threadIdx.x;
    const float* x = in + (size_t)row * H_;
    float v[3], s0 = 0.f, s1 = 0.f;
    #pragma unroll
    for (int r = 0; r < 3; ++r) {
        v[r] = x[tid + r * 256];
        s0 += v[r]; s1 += v[r] * v[r];
    }
    __shared__ float red[8];
    __shared__ float stat[2];
    #pragma unroll
    for (int o = 32; o > 0; o >>= 1) { s0 += __shfl_down(s0, o); s1 += __shfl_down(s1, o); }
    if ((tid & 63) == 0) { red[tid >> 6] = s0; red[4 + (tid >> 6)] = s1; }
    __syncthreads();
    if (tid == 0) {
        float t0 = red[0] + red[1] + red[2] + red[3];
        float t1 = red[4] + red[5] + red[6] + red[7];
        float mean = t0 / H_;
        float var  = t1 / H_ - mean * mean;
        stat[0] = mean;
        stat[1] = rsqrtf(var + 1e-12f);
    }
    __syncthreads();
    float mean = stat[0], rstd = stat[1];
    float* o = out + (size_t)row * H_;
    unsigned short* ob = outb + (size_t)row * H_;
    #pragma unroll
    for (int r = 0; r < 3; ++r) {
        int i = tid + r * 256;
        float rr = (v[r] - mean) * rstd * sc[i] + bi[i];
        o[i] = rr;
        ob[i] = f2bf(rr);
    }
}

__global__ __launch_bounds__(256) void embed_ln_kernel(
    const int* __restrict__ ids, const float* __restrict__ tok,
    const float* __restrict__ pos, const float* __restrict__ sc,
    const float* __restrict__ bi, float* __restrict__ out,
    unsigned short* __restrict__ outb)
{
    const int row = blockIdx.x;
    const int spos = row & (S_ - 1);
    const int tid = threadIdx.x;
    const int id = ids[row];
    const float* t = tok + (size_t)id * H_;
    const float* p = pos + (size_t)spos * H_;
    float v[3], s0 = 0.f, s1 = 0.f;
    #pragma unroll
    for (int r = 0; r < 3; ++r) {
        int i = tid + r * 256;
        v[r] = t[i] + p[i];
        s0 += v[r]; s1 += v[r] * v[r];
    }
    __shared__ float red[8];
    __shared__ float stat[2];
    #pragma unroll
    for (int o = 32; o > 0; o >>= 1) { s0 += __shfl_down(s0, o); s1 += __shfl_down(s1, o); }
    if ((tid & 63) == 0) { red[tid >> 6] = s0; red[4 + (tid >> 6)] = s1; }
    __syncthreads();
    if (tid == 0) {
        float t0 = red[0] + red[1] + red[2] + red[3];
        float t1 = red[4] + red[5] + red[6] + red[7];
        float mean = t0 / H_;
        float var  = t1 / H_ - mean * mean;
        stat[0] = mean;
        stat[1] = rsqrtf(var + 1e-12f);
    }
    __syncthreads();
    float mean = stat[0], rstd = stat[1];
    float* o = out + (size_t)row * H_;
    unsigned short* ob = outb + (size_t)row * H_;
    #pragma unroll
    for (int r = 0; r < 3; ++r) {
        int i = tid + r * 256;
        float rr = (v[r] - mean) * rstd * sc[i] + bi[i];
        o[i] = rr;
        ob[i] = f2bf(rr);
    }
}

// ---------------------------------------------------------------------------
// Classifier GEMM (N=19): 32 threads/row (19 active), W staged in LDS,
// fp32 math identical to previous version. 512 blocks -> latency-tolerant.
// ---------------------------------------------------------------------------
__global__ __launch_bounds__(256) void gemm_cls(
    const float* __restrict__ A, const float* __restrict__ W,
    const float* __restrict__ bias, float* __restrict__ C)
{
    __shared__ float Ws[H_ * NL_];     // 57 KB: W[k][n] row-major
    const int tid = threadIdx.x;
    for (int i = tid; i < H_ * NL_; i += 256) Ws[i] = W[i];
    __syncthreads();

    const int g   = blockIdx.x * 256 + tid;
    const int row = g >> 5;
    const int col = g & 31;
    if (col >= NL_) return;

    const float* a = A + (size_t)row * H_;
    float acc = 0.f;
    for (int k = 0; k < H_; k += 4) {
        f32x4 a4 = *(const f32x4*)(a + k);
        acc = fmaf(a4[0], Ws[(k + 0) * NL_ + col],
              fmaf(a4[1], Ws[(k + 1) * NL_ + col],
              fmaf(a4[2], Ws[(k + 2) * NL_ + col],
              fmaf(a4[3], Ws[(k + 3) * NL_ + col], acc))));
    }
    C[(size_t)row * NL_ + col] = acc + bias[col];
}

// ---------------------------------------------------------------------------
// CRF numerator per batch
// ---------------------------------------------------------------------------
__global__ __launch_bounds__(256) void crf_num_kernel(
    const float* __restrict__ logits, const int* __restrict__ labels,
    const int* __restrict__ mask, const float* __restrict__ start_trans,
    const float* __restrict__ end_trans, const float* __restrict__ trans,
    float* __restrict__ numb)
{
    const int b = blockIdx.x;
    const int tid = threadIdx.x;
    float lsum = 0.f, lmask = 0.f;
    for (int t = tid; t < S_; t += 256) {
        float mf = (float)mask[b * S_ + t];
        lmask += mf;
        if (t >= 1) {
            int lp = labels[b * S_ + t - 1];
            int lc = labels[b * S_ + t];
            float em = logits[((size_t)b * S_ + t) * NL_ + lc];
            lsum += (trans[lp * NL_ + lc] + em) * mf;
        }
    }
    __shared__ float red[8];
    #pragma unroll
    for (int o = 32; o > 0; o >>= 1) { lsum += __shfl_down(lsum, o); lmask += __shfl_down(lmask, o); }
    if ((tid & 63) == 0) { red[tid >> 6] = lsum; red[4 + (tid >> 6)] = lmask; }
    __syncthreads();
    if (tid == 0) {
        float ts = red[0] + red[1] + red[2] + red[3];
        float tm = red[4] + red[5] + red[6] + red[7];
        int l0 = labels[b * S_];
        float nm = start_trans[l0] + logits[(size_t)b * S_ * NL_ + l0] + ts;
        int last = (int)tm - 1;
        int lt = labels[b * S_ + last];
        nm += end_trans[lt];
        numb[b] = nm;
    }
}

// ---------------------------------------------------------------------------
// CRF forward, parallel scan in log-semiring (chunk + tree combine).
// ---------------------------------------------------------------------------
__global__ __launch_bounds__(384) void crf_chunk_kernel(
    const float* __restrict__ logits, const int* __restrict__ mask,
    const float* __restrict__ trans, float* __restrict__ Pg)
{
    const int c = blockIdx.x, b = blockIdx.y;
    const int tid = threadIdx.x;
    const bool act = tid < NL_ * NL_;
    const int i = tid / NL_;
    const int j = tid - i * NL_;

    const int t0 = 1 + c * CHL_;
    const int nt = min(CHL_, S_ - t0);

    __shared__ float P[NL_][20];
    __shared__ float tr_s[NL_ * NL_];
    __shared__ float em_s[CHL_ * NL_];
    __shared__ int mk[CHL_];

    for (int f = tid; f < NL_ * NL_; f += 384) tr_s[f] = trans[f];
    for (int f = tid; f < nt * NL_; f += 384)
        em_s[f] = logits[((size_t)b * S_ + t0) * NL_ + f];
    if (tid < nt) mk[tid] = mask[b * S_ + t0 + tid];
    __syncthreads();

    float trcol[NL_];
    if (act) {
        #pragma unroll
        for (int k = 0; k < NL_; ++k) trcol[k] = tr_s[k * NL_ + j];
        float p0;
        if (mk[0] > 0) p0 = tr_s[i * NL_ + j] + em_s[j];
        else           p0 = (i == j) ? 0.f : -1e30f;
        P[i][j] = p0;
    }
    __syncthreads();

    for (int tt = 1; tt < nt; ++tt) {
        float nv = 0.f;
        if (act) {
            float v[NL_];
            float vmax = -3e38f;
            #pragma unroll
            for (int k = 0; k < NL_; ++k) {
                v[k] = P[i][k] + trcol[k];
                vmax = fmaxf(vmax, v[k]);
            }
            float s = 0.f;
            #pragma unroll
            for (int k = 0; k < NL_; ++k) s += __expf(v[k] - vmax);
            nv = vmax + __logf(s) + em_s[tt * NL_ + j];
        }
        __syncthreads();
        if (act && mk[tt] > 0) P[i][j] = nv;
        __syncthreads();
    }

    if (act) Pg[((size_t)b * NCH_ + c) * (NL_ * NL_) + tid] = P[i][j];
}

__global__ __launch_bounds__(384) void crf_combine_kernel(
    const float* __restrict__ Pg, const float* __restrict__ logits,
    const float* __restrict__ start_trans, const float* __restrict__ end_trans,
    float* __restrict__ denb)
{
    const int b = blockIdx.x;
    const int tid = threadIdx.x;
    __shared__ float Q[NCH_ * NL_ * NL_];
    __shared__ float fin[NL_];

    for (int w = tid; w < NCH_ * NL_ * NL_; w += 384)
        Q[w] = Pg[(size_t)b * NCH_ * NL_ * NL_ + w];
    __syncthreads();

    for (int m = NCH_ / 2; m >= 1; m >>= 1) {
        const int items = m * NL_ * NL_;
        float res[16];
        #pragma unroll
        for (int r = 0; r < 16; ++r) {
            const int w = tid + r * 384;
            if (w < items) {
                const int p = w / (NL_ * NL_);
                const int e = w - p * (NL_ * NL_);
                const int ii = e / NL_;
                const int jj = e - ii * NL_;
                const float* Lm = &Q[(2 * p) * NL_ * NL_ + ii * NL_];
                const float* Rm = &Q[(2 * p + 1) * NL_ * NL_ + jj];
                float v[NL_];
                float vmax = -3e38f;
                #pragma unroll
                for (int k = 0; k < NL_; ++k) {
                    v[k] = Lm[k] + Rm[k * NL_];
                    vmax = fmaxf(vmax, v[k]);
                }
                float s = 0.f;
                #pragma unroll
                for (int k = 0; k < NL_; ++k) s += __expf(v[k] - vmax);
                res[r] = vmax + __logf(s);
            }
        }
        __syncthreads();
        #pragma unroll
        for (int r = 0; r < 16; ++r) {
            const int w = tid + r * 384;
            if (w < items) Q[w] = res[r];
        }
        __syncthreads();
    }

    if (tid < NL_) {
        float v[NL_];
        float vmax = -3e38f;
        #pragma unroll
        for (int k = 0; k < NL_; ++k) {
            v[k] = start_trans[k] + logits[(size_t)b * S_ * NL_ + k] + Q[k * NL_ + tid];
            vmax = fmaxf(vmax, v[k]);
        }
        float s = 0.f;
        #pragma unroll
        for (int k = 0; k < NL_; ++k) s += __expf(v[k] - vmax);
        fin[tid] = vmax + __logf(s) + end_trans[tid];
    }
    __syncthreads();
    if (tid == 0) {
        float vmax = -3e38f;
        #pragma unroll
        for (int k = 0; k < NL_; ++k) vmax = fmaxf(vmax, fin[k]);
        float s = 0.f;
        #pragma unroll
        for (int k = 0; k < NL_; ++k) s += __expf(fin[k] - vmax);
        denb[b] = vmax + __logf(s);
    }
}

__global__ void finalize_kernel(const float* __restrict__ numb,
                                const float* __restrict__ denb,
                                float* __restrict__ out)
{
    if (threadIdx.x == 0 && blockIdx.x == 0) {
        float s = 0.f;
        for (int b = 0; b < B_; ++b) s += denb[b] - numb[b];
        out[0] = s;
    }
}

// ---------------------------------------------------------------------------
extern "C" void kernel_launch(void* const* d_in, const int* in_sizes, int n_in,
                              void* d_out, int out_size, void* d_ws, size_t ws_size,
                              hipStream_t stream)
{
    const int*   input_ids = (const int*)d_in[0];
    const int*   attn_mask = (const int*)d_in[1];
    const int*   labels    = (const int*)d_in[2];
    const float* token_emb = (const float*)d_in[3];
    const float* pos_emb   = (const float*)d_in[4];
    const float* ln_emb_s  = (const float*)d_in[5];
    const float* ln_emb_b  = (const float*)d_in[6];
    const float* Wq  = (const float*)d_in[7];
    const float* bq  = (const float*)d_in[8];
    const float* Wk  = (const float*)d_in[9];
    const float* bk  = (const float*)d_in[10];
    const float* Wv  = (const float*)d_in[11];
    const float* bv  = (const float*)d_in[12];
    const float* Wo  = (const float*)d_in[13];
    const float* bo  = (const float*)d_in[14];
    const float* ln1s = (const float*)d_in[15];
    const float* ln1b = (const float*)d_in[16];
    const float* W1  = (const float*)d_in[17];
    const float* b1  = (const float*)d_in[18];
    const float* W2  = (const float*)d_in[19];
    const float* b2  = (const float*)d_in[20];
    const float* ln2s = (const float*)d_in[21];
    const float* ln2b = (const float*)d_in[22];
    const float* cls_W = (const float*)d_in[23];
    const float* cls_b = (const float*)d_in[24];
    const float* start_trans = (const float*)d_in[25];
    const float* end_trans   = (const float*)d_in[26];
    const float* trans       = (const float*)d_in[27];

    char* base = (char*)d_ws;
    const int M = B_ * S_;                                  // 4096
    // region0 (25.17 MB): qkvb[M][2304] + vtb[96][64][512] bf16 during attn,
    // aliased by hbb[M][3072] bf16 during FFN (disjoint lifetimes; same size).
    unsigned short* qkvb = (unsigned short*)base;
    unsigned short* vtb  = qkvb + (size_t)M * 2304;
    unsigned short* hbb  = (unsigned short*)base;
    size_t off = (size_t)M * 3072 * 2;
    float*          x     = (float*)(base + off); off += (size_t)M * H_ * 4;
    float*          y     = (float*)(base + off); off += (size_t)M * H_ * 4;
    unsigned short* xb    = (unsigned short*)(base + off); off += (size_t)M * H_ * 2;
    unsigned short* ctxb  = (unsigned short*)(base + off); off += (size_t)M * H_ * 2;
    unsigned short* WqkvT = (unsigned short*)(base + off); off += (size_t)3 * H_ * H_ * 2;
    unsigned short* WoT   = (unsigned short*)(base + off); off += (size_t)H_ * H_ * 2;
    unsigned short* W1T   = (unsigned short*)(base + off); off += (size_t)DFF_ * H_ * 2;
    unsigned short* W2T   = (unsigned short*)(base + off); off += (size_t)H_ * DFF_ * 2;
    float*          biasc = (float*)(base + off); off += 3 * H_ * 4 + 256;
    float*          logits= (float*)(base + off); off += (size_t)M * NL_ * 4;
    float*          numb  = (float*)(base + off); off += 32;
    float*          denb  = (float*)(base + off); off += 32;
    float*          Pg    = (float*)(base + off); off += (size_t)B_ * NCH_ * NL_ * NL_ * 4;

    dim3 blk(256);
    embed_ln_kernel<<<M, blk, 0, stream>>>(input_ids, token_emb, pos_emb, ln_emb_s, ln_emb_b, x, xb);

    for (int l = 0; l < L_; ++l) {
        const size_t oHH = (size_t)l * H_ * H_;
        const size_t oHF = (size_t)l * H_ * DFF_;
        prep_layer<<<1737, blk, 0, stream>>>(
            Wq + oHH, Wk + oHH, Wv + oHH, Wo + oHH, W1 + oHF, W2 + oHF,
            bq + l * H_, bk + l * H_, bv + l * H_,
            WqkvT, WoT, W1T, W2T, biasc);

        gemm_bf16<3><<<dim3(18, 32), blk, 0, stream>>>(xb, WqkvT, biasc, nullptr, nullptr, qkvb, vtb, M, 3 * H_, H_);
        attn3<<<dim3(8, NHD_, B_), blk, 0, stream>>>(qkvb, vtb, attn_mask, ctxb);
        gemm_bf16<2><<<dim3(6, 32), blk, 0, stream>>>(ctxb, WoT, bo + l * H_, x, y, nullptr, nullptr, M, H_, H_);
        ln_kernel<<<M, blk, 0, stream>>>(y, ln1s + l * H_, ln1b + l * H_, x, xb);
        gemm_bf16<1><<<dim3(24, 32), blk, 0, stream>>>(xb, W1T, b1 + l * DFF_, nullptr, nullptr, hbb, nullptr, M, DFF_, H_);
        gemm_bf16<2><<<dim3(6, 32), blk, 0, stream>>>(hbb, W2T, b2 + l * H_, x, y, nullptr, nullptr, M, H_, DFF_);
        ln_kernel<<<M, blk, 0, stream>>>(y, ln2s + l * H_, ln2b + l * H_, x, xb);
    }

    gemm_cls<<<dim3(M * 32 / 256), blk, 0, stream>>>(x, cls_W, cls_b, logits);
    crf_num_kernel<<<B_, blk, 0, stream>>>(logits, labels, attn_mask, start_trans, end_trans, trans, numb);
    crf_chunk_kernel<<<dim3(NCH_, B_), dim3(384), 0, stream>>>(logits, attn_mask, trans, Pg);
    crf_combine_kernel<<<B_, dim3(384), 0, stream>>>(Pg, logits, start_trans, end_trans, denb);
    finalize_kernel<<<1, 64, 0, stream>>>(numb, denb, (float*)d_out);
}